// Round 2
// baseline (915.585 us; speedup 1.0000x reference)
//
#include <hip/hip_runtime.h>
#include <math.h>

#define N_NODES 50000
#define N_EDGES 400000
#define E_TOT   450000     // edges + self loops
#define DIM_IN  768
#define HC      256        // heads * dim_h = 8*32
#define D2      16

__device__ __forceinline__ float lrelu(float x) { return x > 0.f ? x : 0.2f * x; }

// ---------------- GEMM1: xlr[i][0:256] = x@W1l, xlr[i][256:512] = x@W1r ----
__global__ __launch_bounds__(256) void gemm1_kernel(
    const float* __restrict__ x, const float* __restrict__ W1l,
    const float* __restrict__ W1r, float* __restrict__ xlr) {
  __shared__ float As[16][68];   // [k][row], padded
  __shared__ float Bs[16][68];   // [k][col], padded (stride 68 keeps 16B align)
  const int bm0 = blockIdx.x * 64;
  const int bn0 = blockIdx.y * 64;
  const float* B = (bn0 < HC) ? (W1l + bn0) : (W1r + (bn0 - HC));
  const int t = threadIdx.x;
  const int tm = (t >> 4) * 4;       // row group
  const int tn = (t & 15) * 4;       // col group
  const int a_row = t >> 2;          // 0..63
  const int a_k = (t & 3) * 4;
  const int b_k = t >> 4;            // 0..15
  const int b_c = (t & 15) * 4;
  float acc[4][4] = {};
  for (int k0 = 0; k0 < DIM_IN; k0 += 16) {
    float4 av;
    const int grow = bm0 + a_row;
    if (grow < N_NODES)
      av = *(const float4*)(x + (size_t)grow * DIM_IN + k0 + a_k);
    else
      av = make_float4(0.f, 0.f, 0.f, 0.f);
    As[a_k + 0][a_row] = av.x;
    As[a_k + 1][a_row] = av.y;
    As[a_k + 2][a_row] = av.z;
    As[a_k + 3][a_row] = av.w;
    *(float4*)&Bs[b_k][b_c] = *(const float4*)(B + (size_t)(k0 + b_k) * HC + b_c);
    __syncthreads();
#pragma unroll
    for (int kk = 0; kk < 16; ++kk) {
      float a[4], b[4];
#pragma unroll
      for (int i = 0; i < 4; ++i) a[i] = As[kk][tm + i];
#pragma unroll
      for (int j = 0; j < 4; ++j) b[j] = Bs[kk][tn + j];
#pragma unroll
      for (int i = 0; i < 4; ++i)
#pragma unroll
        for (int j = 0; j < 4; ++j) acc[i][j] += a[i] * b[j];
    }
    __syncthreads();
  }
#pragma unroll
  for (int i = 0; i < 4; ++i) {
    const int row = bm0 + tm + i;
    if (row < N_NODES)
      *(float4*)(xlr + (size_t)row * 512 + bn0 + tn) =
          make_float4(acc[i][0], acc[i][1], acc[i][2], acc[i][3]);
  }
}

// ---------------- CSR build ------------------------------------------------
__global__ void init_deg_kernel(int* __restrict__ deg) {
  int i = blockIdx.x * blockDim.x + threadIdx.x;
  if (i < N_NODES) deg[i] = 1;   // self loop
}

__global__ void hist_kernel(const int* __restrict__ dst, int* __restrict__ deg) {
  int e = blockIdx.x * blockDim.x + threadIdx.x;
  if (e < N_EDGES) atomicAdd(&deg[dst[e]], 1);
}

__global__ __launch_bounds__(1024) void scan_kernel(
    const int* __restrict__ deg, int* __restrict__ offsets, int* __restrict__ cursor) {
  __shared__ int wsum[16];
  __shared__ int wpre[16];
  __shared__ int scarry;
  const int t = threadIdx.x, lane = t & 63, wid = t >> 6;
  if (t == 0) scarry = 0;
  __syncthreads();
  for (int base = 0; base < N_NODES; base += 1024) {
    const int idx = base + t;
    const int v = (idx < N_NODES) ? deg[idx] : 0;
    int inc = v;
#pragma unroll
    for (int d = 1; d < 64; d <<= 1) {
      int n = __shfl_up(inc, d);
      if (lane >= d) inc += n;
    }
    if (lane == 63) wsum[wid] = inc;
    __syncthreads();
    if (t < 16) {
      int wv = wsum[t];
      int winc = wv;
#pragma unroll
      for (int d = 1; d < 16; d <<= 1) {
        int n = __shfl_up(winc, d);
        if (t >= d) winc += n;
      }
      wpre[t] = winc - wv;          // exclusive wave prefix
      if (t == 15) wsum[15] = winc; // chunk total
    }
    __syncthreads();
    const int excl = scarry + wpre[wid] + inc - v;
    if (idx < N_NODES) { offsets[idx] = excl; cursor[idx] = excl; }
    __syncthreads();
    if (t == 15) scarry += wsum[15];
    __syncthreads();
  }
  if (t == 0) offsets[N_NODES] = scarry;
}

__global__ void scatter_kernel(const int* __restrict__ src, const int* __restrict__ dst,
                               int* __restrict__ cursor, int* __restrict__ ssrc) {
  int e = blockIdx.x * blockDim.x + threadIdx.x;
  if (e >= E_TOT) return;
  int d, s;
  if (e < N_EDGES) { d = dst[e]; s = src[e]; }
  else { d = e - N_EDGES; s = d; }
  int pos = atomicAdd(&cursor[d], 1);
  ssrc[pos] = s;
}

// ---------------- Layer 1: one wave per node, online softmax --------------
__global__ __launch_bounds__(256) void layer1_kernel(
    const float* __restrict__ xlr, const int* __restrict__ offsets,
    const int* __restrict__ ssrc, const float* __restrict__ att1,
    const float* __restrict__ b1, float* __restrict__ h) {
  const int wid = (blockIdx.x * blockDim.x + threadIdx.x) >> 6;
  const int lane = threadIdx.x & 63;
  if (wid >= N_NODES) return;
  const int i = wid;
  const float4 xr = *(const float4*)(xlr + (size_t)i * 512 + HC + (lane << 2));
  const float4 av = *(const float4*)(att1 + (lane << 2));
  const int e0 = offsets[i], e1 = offsets[i + 1];
  float m = -INFINITY, s = 0.f;
  float acc0 = 0.f, acc1 = 0.f, acc2 = 0.f, acc3 = 0.f;
  int j = ssrc[e0];   // every node has >=1 edge (self loop)
  for (int e = e0; e < e1; ++e) {
    const int jn = (e + 1 < e1) ? ssrc[e + 1] : 0;
    const float4 v = *(const float4*)(xlr + (size_t)j * 512 + (lane << 2));
    float p = lrelu(v.x + xr.x) * av.x + lrelu(v.y + xr.y) * av.y +
              lrelu(v.z + xr.z) * av.z + lrelu(v.w + xr.w) * av.w;
    p += __shfl_xor(p, 1);
    p += __shfl_xor(p, 2);
    p += __shfl_xor(p, 4);     // per-head score, replicated in 8-lane group
    if (p > m) {
      const float f = __expf(m - p);   // m==-inf -> 0
      s *= f; acc0 *= f; acc1 *= f; acc2 *= f; acc3 *= f;
      m = p;
    }
    const float w = __expf(p - m);
    s += w;
    acc0 += w * v.x; acc1 += w * v.y; acc2 += w * v.z; acc3 += w * v.w;
    j = jn;
  }
  const float inv = 1.f / s;
  float r0 = acc0 * inv + b1[(lane << 2) + 0];
  float r1 = acc1 * inv + b1[(lane << 2) + 1];
  float r2 = acc2 * inv + b1[(lane << 2) + 2];
  float r3 = acc3 * inv + b1[(lane << 2) + 3];
  // ELU
  r0 = r0 > 0.f ? r0 : __expf(r0) - 1.f;
  r1 = r1 > 0.f ? r1 : __expf(r1) - 1.f;
  r2 = r2 > 0.f ? r2 : __expf(r2) - 1.f;
  r3 = r3 > 0.f ? r3 : __expf(r3) - 1.f;
  *(float4*)(h + (size_t)i * HC + (lane << 2)) = make_float4(r0, r1, r2, r3);
}

// ---------------- GEMM2: xl2 = h@W2l, xr2 = h@W2r (K=256 -> 16) -----------
__global__ __launch_bounds__(256) void gemm2_kernel(
    const float* __restrict__ h, const float* __restrict__ W2l,
    const float* __restrict__ W2r, float* __restrict__ xl2, float* __restrict__ xr2) {
  __shared__ float Wl[HC * D2];
  __shared__ float Wr[HC * D2];
  __shared__ float hrow[16 * (HC + 4)];   // padded rows: no 4-way bank conflict
  const int t = threadIdx.x;
  for (int idx = t; idx < HC * D2; idx += 256) { Wl[idx] = W2l[idx]; Wr[idx] = W2r[idx]; }
  const int nodeBase = blockIdx.x * 16;
  for (int idx = t; idx < 16 * HC; idx += 256) {
    const int r = idx >> 8, c = idx & 255;
    hrow[r * (HC + 4) + c] = h[(size_t)nodeBase * HC + idx];
  }
  __syncthreads();
  const int ln = t >> 4;
  const int c = t & 15;
  const float* hp = hrow + ln * (HC + 4);
  float al = 0.f, ar = 0.f;
#pragma unroll 8
  for (int k = 0; k < HC; ++k) {
    const float hv = hp[k];
    al += hv * Wl[k * D2 + c];
    ar += hv * Wr[k * D2 + c];
  }
  const int node = nodeBase + ln;
  xl2[node * D2 + c] = al;
  xr2[node * D2 + c] = ar;
}

// ---------------- Layer 2 + log_softmax: 16 lanes per node ----------------
__global__ __launch_bounds__(256) void layer2_kernel(
    const float* __restrict__ xl2, const float* __restrict__ xr2,
    const int* __restrict__ offsets, const int* __restrict__ ssrc,
    const float* __restrict__ att2, const float* __restrict__ b2,
    float* __restrict__ out) {
  const int gtid = blockIdx.x * blockDim.x + threadIdx.x;
  const int node = gtid >> 4;
  const int c = gtid & 15;
  if (node >= N_NODES) return;
  const float xr = xr2[node * D2 + c];
  const float av = att2[c];
  const int e0 = offsets[node], e1 = offsets[node + 1];
  float m = -INFINITY, s = 0.f, acc = 0.f;
  for (int e = e0; e < e1; ++e) {
    const int j = ssrc[e];
    const float v = xl2[j * D2 + c];
    float p = lrelu(v + xr) * av;
    p += __shfl_xor(p, 1);
    p += __shfl_xor(p, 2);
    p += __shfl_xor(p, 4);
    p += __shfl_xor(p, 8);     // score for this node, replicated in 16-lane group
    if (p > m) {
      const float f = __expf(m - p);
      s *= f; acc *= f;
      m = p;
    }
    const float w = __expf(p - m);
    s += w;
    acc += w * v;
  }
  const float o = acc / s + b2[c];
  out[(size_t)node * D2 + c] = o;
  // log_softmax over the 16 channels of this node
  float mx = o;
#pragma unroll
  for (int d = 1; d < 16; d <<= 1) mx = fmaxf(mx, __shfl_xor(mx, d));
  float ex = __expf(o - mx);
  float sum = ex;
#pragma unroll
  for (int d = 1; d < 16; d <<= 1) sum += __shfl_xor(sum, d);
  out[(size_t)N_NODES * D2 + (size_t)node * D2 + c] = o - mx - __logf(sum);
}

// ---------------- launch ---------------------------------------------------
extern "C" void kernel_launch(void* const* d_in, const int* in_sizes, int n_in,
                              void* d_out, int out_size, void* d_ws, size_t ws_size,
                              hipStream_t stream) {
  const float* x    = (const float*)d_in[0];
  const int*   ei   = (const int*)d_in[1];
  const float* W1l  = (const float*)d_in[2];
  const float* W1r  = (const float*)d_in[3];
  const float* att1 = (const float*)d_in[4];
  const float* b1   = (const float*)d_in[5];
  const float* W2l  = (const float*)d_in[6];
  const float* W2r  = (const float*)d_in[7];
  const float* att2 = (const float*)d_in[8];
  const float* b2   = (const float*)d_in[9];
  const int* esrc = ei;
  const int* edst = ei + N_EDGES;
  float* out = (float*)d_out;

  char* ws = (char*)d_ws;
  float* xlr = (float*)ws;              ws += (size_t)N_NODES * 512 * 4;  // 102.4 MB
  float* h   = (float*)ws;              ws += (size_t)N_NODES * HC * 4;   // 51.2 MB
  float* xl2 = (float*)ws;              ws += (size_t)N_NODES * D2 * 4;
  float* xr2 = (float*)ws;              ws += (size_t)N_NODES * D2 * 4;
  int* deg     = (int*)ws;              ws += 200192;
  int* offsets = (int*)ws;              ws += 200192;
  int* cursor  = (int*)ws;              ws += 200192;
  int* ssrc    = (int*)ws;              ws += (size_t)E_TOT * 4;

  gemm1_kernel<<<dim3((N_NODES + 63) / 64, 8), 256, 0, stream>>>(x, W1l, W1r, xlr);
  init_deg_kernel<<<(N_NODES + 255) / 256, 256, 0, stream>>>(deg);
  hist_kernel<<<(N_EDGES + 255) / 256, 256, 0, stream>>>(edst, deg);
  scan_kernel<<<1, 1024, 0, stream>>>(deg, offsets, cursor);
  scatter_kernel<<<(E_TOT + 255) / 256, 256, 0, stream>>>(esrc, edst, cursor, ssrc);
  layer1_kernel<<<(N_NODES * 64 + 255) / 256, 256, 0, stream>>>(xlr, offsets, ssrc, att1, b1, h);
  gemm2_kernel<<<N_NODES / 16, 256, 0, stream>>>(h, W2l, W2r, xl2, xr2);
  layer2_kernel<<<(N_NODES * D2 + 255) / 256, 256, 0, stream>>>(xl2, xr2, offsets, ssrc, att2, b2, out);
}

// Round 4
// 556.886 us; speedup vs baseline: 1.6441x; 1.6441x over previous
//
#include <hip/hip_runtime.h>
#include <math.h>

#define N_NODES 50000
#define N_EDGES 400000
#define E_TOT   450000     // edges + self loops
#define DIM_IN  768
#define HC      256        // heads * dim_h = 8*32
#define D2      16
#define NB      512        // gemm1 output cols (xl | xr)

typedef __attribute__((ext_vector_type(8))) short short8v;   // 8 bf16 (4 VGPR)
typedef __attribute__((ext_vector_type(4))) float f32x4;     // MFMA acc

__device__ __forceinline__ float lrelu(float x) { return x > 0.f ? x : 0.2f * x; }

// fp32 -> bf16 round-to-nearest-even
__device__ __forceinline__ unsigned short f2bf(float f) {
  unsigned int u = __float_as_uint(f);
  unsigned int r = u + 0x7fffu + ((u >> 16) & 1u);
  return (unsigned short)(r >> 16);
}

// ---------------- convert x to bf16 ---------------------------------------
__global__ __launch_bounds__(256) void convx_kernel(
    const float* __restrict__ x, unsigned short* __restrict__ xb) {
  const int ntask = (N_NODES * DIM_IN) / 8;   // 4.8M tasks of 8 elems
  const int stride = gridDim.x * blockDim.x;
  for (int i = blockIdx.x * blockDim.x + threadIdx.x; i < ntask; i += stride) {
    const float4 a = ((const float4*)x)[2 * (size_t)i];
    const float4 b = ((const float4*)x)[2 * (size_t)i + 1];
    short8v v;
    v[0] = (short)f2bf(a.x); v[1] = (short)f2bf(a.y);
    v[2] = (short)f2bf(a.z); v[3] = (short)f2bf(a.w);
    v[4] = (short)f2bf(b.x); v[5] = (short)f2bf(b.y);
    v[6] = (short)f2bf(b.z); v[7] = (short)f2bf(b.w);
    ((short8v*)xb)[i] = v;
  }
}

// ---------------- build WcatT[512][768] = [W1l | W1r]^T in bf16 -----------
__global__ __launch_bounds__(256) void convw_kernel(
    const float* __restrict__ W1l, const float* __restrict__ W1r,
    unsigned short* __restrict__ wt) {
  const int idx = blockIdx.x * 256 + threadIdx.x;
  if (idx >= NB * DIM_IN) return;
  const int n = idx / DIM_IN, k = idx - n * DIM_IN;
  const float v = (n < HC) ? W1l[(size_t)k * HC + n] : W1r[(size_t)k * HC + (n - HC)];
  wt[idx] = f2bf(v);  // writes coalesced along k
}

// ---------------- GEMM1 (bf16 MFMA): xlr = x @ [W1l|W1r] -------------------
// 128x128 tile, BK=64, 4 waves (2x2), global_load_lds staging with
// pre-swizzled global source + XOR-swizzled ds_read (linear LDS dest).
__global__ __launch_bounds__(256) void gemm1_mfma(
    const unsigned short* __restrict__ xb, const unsigned short* __restrict__ wt,
    float* __restrict__ xlr) {
  __shared__ unsigned short Al[128 * 64];   // 16 KB, rows of 64 bf16 (128 B)
  __shared__ unsigned short Bl[128 * 64];   // 16 KB, rows = output cols
  const int t = threadIdx.x;
  const int lane = t & 63;
  const int w = t >> 6;            // wave 0..3
  const int wr = w >> 1, wc = w & 1;
  const int bm0 = blockIdx.x * 128;
  const int bn0 = blockIdx.y * 128;

  // staging geometry: wave handles rowgroups rg = w*4+q (8 rows x 128 B each)
  const int r8 = lane >> 3;                         // row within group 0..7
  const int swz_cb = ((lane & 7) << 4) ^ (r8 << 4); // pre-swizzled source col byte

  f32x4 acc[4][4];
#pragma unroll
  for (int m = 0; m < 4; ++m)
#pragma unroll
    for (int n = 0; n < 4; ++n) acc[m][n] = (f32x4)0.f;

  const int fr = lane & 15;     // frag row/col
  const int kg = lane >> 4;     // k-group 0..3
  const int swr = (fr & 7) << 4;

  for (int k0 = 0; k0 < DIM_IN; k0 += 64) {
    __syncthreads();   // previous compute finished before overwrite
#pragma unroll
    for (int q = 0; q < 4; ++q) {
      const int rg = w * 4 + q;
      int grow = bm0 + rg * 8 + r8;
      grow = grow < N_NODES ? grow : N_NODES - 1;   // clamp (dup rows, stores guarded)
      const char* src = (const char*)(xb + (size_t)grow * DIM_IN + k0) + swz_cb;
      __builtin_amdgcn_global_load_lds(
          (const __attribute__((address_space(1))) void*)src,
          (__attribute__((address_space(3))) void*)((char*)Al + rg * 1024), 16, 0, 0);
    }
#pragma unroll
    for (int q = 0; q < 4; ++q) {
      const int rg = w * 4 + q;
      const int brow = bn0 + rg * 8 + r8;
      const char* src = (const char*)(wt + (size_t)brow * DIM_IN + k0) + swz_cb;
      __builtin_amdgcn_global_load_lds(
          (const __attribute__((address_space(1))) void*)src,
          (__attribute__((address_space(3))) void*)((char*)Bl + rg * 1024), 16, 0, 0);
    }
    __syncthreads();   // staged tile visible (barrier drains vmcnt)

    short8v af[4][2], bf[4][2];
#pragma unroll
    for (int m = 0; m < 4; ++m) {
      const int row = wr * 64 + m * 16 + fr;
#pragma unroll
      for (int ks = 0; ks < 2; ++ks) {
        const int cb = (ks * 64 + kg * 16) ^ swr;
        af[m][ks] = *(const short8v*)((const char*)Al + row * 128 + cb);
      }
    }
#pragma unroll
    for (int n = 0; n < 4; ++n) {
      const int row = wc * 64 + n * 16 + fr;
#pragma unroll
      for (int ks = 0; ks < 2; ++ks) {
        const int cb = (ks * 64 + kg * 16) ^ swr;
        bf[n][ks] = *(const short8v*)((const char*)Bl + row * 128 + cb);
      }
    }
#pragma unroll
    for (int ks = 0; ks < 2; ++ks)
#pragma unroll
      for (int m = 0; m < 4; ++m)
#pragma unroll
        for (int n = 0; n < 4; ++n)
          acc[m][n] = __builtin_amdgcn_mfma_f32_16x16x32_bf16(
              af[m][ks], bf[n][ks], acc[m][n], 0, 0, 0);
  }

  // epilogue: C/D map col=lane&15, row=(lane>>4)*4+reg  [m89/m91 verified]
#pragma unroll
  for (int m = 0; m < 4; ++m) {
    const int grow_base = bm0 + wr * 64 + m * 16 + kg * 4;
#pragma unroll
    for (int n = 0; n < 4; ++n) {
      const int gcol = bn0 + wc * 64 + n * 16 + fr;
#pragma unroll
      for (int r = 0; r < 4; ++r) {
        const int grow = grow_base + r;
        if (grow < N_NODES) xlr[(size_t)grow * NB + gcol] = acc[m][n][r];
      }
    }
  }
}

// ---------------- CSR build ------------------------------------------------
__global__ void init_deg_kernel(int* __restrict__ deg) {
  int i = blockIdx.x * blockDim.x + threadIdx.x;
  if (i < N_NODES) deg[i] = 1;   // self loop
}

__global__ void hist_kernel(const int* __restrict__ dst, int* __restrict__ deg) {
  int e = blockIdx.x * blockDim.x + threadIdx.x;
  if (e < N_EDGES) atomicAdd(&deg[dst[e]], 1);
}

__global__ __launch_bounds__(1024) void scan_kernel(
    const int* __restrict__ deg, int* __restrict__ offsets, int* __restrict__ cursor) {
  __shared__ int wsum[16];
  __shared__ int wpre[16];
  __shared__ int scarry;
  const int t = threadIdx.x, lane = t & 63, wid = t >> 6;
  if (t == 0) scarry = 0;
  __syncthreads();
  for (int base = 0; base < N_NODES; base += 1024) {
    const int idx = base + t;
    const int v = (idx < N_NODES) ? deg[idx] : 0;
    int inc = v;
#pragma unroll
    for (int d = 1; d < 64; d <<= 1) {
      int n = __shfl_up(inc, d);
      if (lane >= d) inc += n;
    }
    if (lane == 63) wsum[wid] = inc;
    __syncthreads();
    if (t < 16) {
      int wv = wsum[t];
      int winc = wv;
#pragma unroll
      for (int d = 1; d < 16; d <<= 1) {
        int n = __shfl_up(winc, d);
        if (t >= d) winc += n;
      }
      wpre[t] = winc - wv;          // exclusive wave prefix
      if (t == 15) wsum[15] = winc; // chunk total
    }
    __syncthreads();
    const int excl = scarry + wpre[wid] + inc - v;
    if (idx < N_NODES) { offsets[idx] = excl; cursor[idx] = excl; }
    __syncthreads();
    if (t == 15) scarry += wsum[15];
    __syncthreads();
  }
  if (t == 0) offsets[N_NODES] = scarry;
}

__global__ void scatter_kernel(const int* __restrict__ src, const int* __restrict__ dst,
                               int* __restrict__ cursor, int* __restrict__ ssrc) {
  int e = blockIdx.x * blockDim.x + threadIdx.x;
  if (e >= E_TOT) return;
  int d, s;
  if (e < N_EDGES) { d = dst[e]; s = src[e]; }
  else { d = e - N_EDGES; s = d; }
  int pos = atomicAdd(&cursor[d], 1);
  ssrc[pos] = s;
}

// ---------------- Layer 1: one wave per node, online softmax --------------
__global__ __launch_bounds__(256) void layer1_kernel(
    const float* __restrict__ xlr, const int* __restrict__ offsets,
    const int* __restrict__ ssrc, const float* __restrict__ att1,
    const float* __restrict__ b1, float* __restrict__ h) {
  const int wid = (blockIdx.x * blockDim.x + threadIdx.x) >> 6;
  const int lane = threadIdx.x & 63;
  if (wid >= N_NODES) return;
  const int i = wid;
  const float4 xr = *(const float4*)(xlr + (size_t)i * 512 + HC + (lane << 2));
  const float4 av = *(const float4*)(att1 + (lane << 2));
  const int e0 = offsets[i], e1 = offsets[i + 1];
  float m = -INFINITY, s = 0.f;
  float acc0 = 0.f, acc1 = 0.f, acc2 = 0.f, acc3 = 0.f;
  int j = ssrc[e0];   // every node has >=1 edge (self loop)
  for (int e = e0; e < e1; ++e) {
    const int jn = (e + 1 < e1) ? ssrc[e + 1] : 0;
    const float4 v = *(const float4*)(xlr + (size_t)j * 512 + (lane << 2));
    float p = lrelu(v.x + xr.x) * av.x + lrelu(v.y + xr.y) * av.y +
              lrelu(v.z + xr.z) * av.z + lrelu(v.w + xr.w) * av.w;
    p += __shfl_xor(p, 1);
    p += __shfl_xor(p, 2);
    p += __shfl_xor(p, 4);     // per-head score, replicated in 8-lane group
    if (p > m) {
      const float f = __expf(m - p);   // m==-inf -> 0
      s *= f; acc0 *= f; acc1 *= f; acc2 *= f; acc3 *= f;
      m = p;
    }
    const float w = __expf(p - m);
    s += w;
    acc0 += w * v.x; acc1 += w * v.y; acc2 += w * v.z; acc3 += w * v.w;
    j = jn;
  }
  const float inv = 1.f / s;
  float r0 = acc0 * inv + b1[(lane << 2) + 0];
  float r1 = acc1 * inv + b1[(lane << 2) + 1];
  float r2 = acc2 * inv + b1[(lane << 2) + 2];
  float r3 = acc3 * inv + b1[(lane << 2) + 3];
  // ELU
  r0 = r0 > 0.f ? r0 : __expf(r0) - 1.f;
  r1 = r1 > 0.f ? r1 : __expf(r1) - 1.f;
  r2 = r2 > 0.f ? r2 : __expf(r2) - 1.f;
  r3 = r3 > 0.f ? r3 : __expf(r3) - 1.f;
  *(float4*)(h + (size_t)i * HC + (lane << 2)) = make_float4(r0, r1, r2, r3);
}

// ---------------- GEMM2: xl2 = h@W2l, xr2 = h@W2r (K=256 -> 16) -----------
__global__ __launch_bounds__(256) void gemm2_kernel(
    const float* __restrict__ h, const float* __restrict__ W2l,
    const float* __restrict__ W2r, float* __restrict__ xl2, float* __restrict__ xr2) {
  __shared__ float Wl[HC * D2];
  __shared__ float Wr[HC * D2];
  __shared__ float hrow[16 * (HC + 4)];   // padded rows: no 4-way bank conflict
  const int t = threadIdx.x;
  for (int idx = t; idx < HC * D2; idx += 256) { Wl[idx] = W2l[idx]; Wr[idx] = W2r[idx]; }
  const int nodeBase = blockIdx.x * 16;
  for (int idx = t; idx < 16 * HC; idx += 256) {
    const int r = idx >> 8, c = idx & 255;
    hrow[r * (HC + 4) + c] = h[(size_t)nodeBase * HC + idx];
  }
  __syncthreads();
  const int ln = t >> 4;
  const int c = t & 15;
  const float* hp = hrow + ln * (HC + 4);
  float al = 0.f, ar = 0.f;
#pragma unroll 8
  for (int k = 0; k < HC; ++k) {
    const float hv = hp[k];
    al += hv * Wl[k * D2 + c];
    ar += hv * Wr[k * D2 + c];
  }
  const int node = nodeBase + ln;
  xl2[node * D2 + c] = al;
  xr2[node * D2 + c] = ar;
}

// ---------------- Layer 2 + log_softmax: 16 lanes per node ----------------
__global__ __launch_bounds__(256) void layer2_kernel(
    const float* __restrict__ xl2, const float* __restrict__ xr2,
    const int* __restrict__ offsets, const int* __restrict__ ssrc,
    const float* __restrict__ att2, const float* __restrict__ b2,
    float* __restrict__ out) {
  const int gtid = blockIdx.x * blockDim.x + threadIdx.x;
  const int node = gtid >> 4;
  const int c = gtid & 15;
  if (node >= N_NODES) return;
  const float xr = xr2[node * D2 + c];
  const float av = att2[c];
  const int e0 = offsets[node], e1 = offsets[node + 1];
  float m = -INFINITY, s = 0.f, acc = 0.f;
  for (int e = e0; e < e1; ++e) {
    const int j = ssrc[e];
    const float v = xl2[j * D2 + c];
    float p = lrelu(v + xr) * av;
    p += __shfl_xor(p, 1);
    p += __shfl_xor(p, 2);
    p += __shfl_xor(p, 4);
    p += __shfl_xor(p, 8);     // score for this node, replicated in 16-lane group
    if (p > m) {
      const float f = __expf(m - p);
      s *= f; acc *= f;
      m = p;
    }
    const float w = __expf(p - m);
    s += w;
    acc += w * v;
  }
  const float o = acc / s + b2[c];
  out[(size_t)node * D2 + c] = o;
  // log_softmax over the 16 channels of this node
  float mx = o;
#pragma unroll
  for (int d = 1; d < 16; d <<= 1) mx = fmaxf(mx, __shfl_xor(mx, d));
  float ex = __expf(o - mx);
  float sum = ex;
#pragma unroll
  for (int d = 1; d < 16; d <<= 1) sum += __shfl_xor(sum, d);
  out[(size_t)N_NODES * D2 + (size_t)node * D2 + c] = o - mx - __logf(sum);
}

// ---------------- launch ---------------------------------------------------
extern "C" void kernel_launch(void* const* d_in, const int* in_sizes, int n_in,
                              void* d_out, int out_size, void* d_ws, size_t ws_size,
                              hipStream_t stream) {
  const float* x    = (const float*)d_in[0];
  const int*   ei   = (const int*)d_in[1];
  const float* W1l  = (const float*)d_in[2];
  const float* W1r  = (const float*)d_in[3];
  const float* att1 = (const float*)d_in[4];
  const float* b1   = (const float*)d_in[5];
  const float* W2l  = (const float*)d_in[6];
  const float* W2r  = (const float*)d_in[7];
  const float* att2 = (const float*)d_in[8];
  const float* b2   = (const float*)d_in[9];
  const int* esrc = ei;
  const int* edst = ei + N_EDGES;
  float* out = (float*)d_out;

  char* ws = (char*)d_ws;
  float* xlr = (float*)ws;                 ws += (size_t)N_NODES * NB * 4;   // 102.4 MB
  // union region: xb (bf16 x) lives only until gemm1; everything below it
  // is written strictly after gemm1 completes (stream-serial order below).
  char* region = ws;                       ws += (size_t)N_NODES * DIM_IN * 2; // 76.8 MB
  unsigned short* xb = (unsigned short*)region;
  float* h   = (float*)region;                                   // 51.2 MB
  float* xl2 = (float*)(region + (size_t)N_NODES * HC * 4);      //  3.2 MB
  float* xr2 = (float*)(region + (size_t)N_NODES * HC * 4 + (size_t)N_NODES * D2 * 4);
  char* intsBase = region + (size_t)N_NODES * HC * 4 + 2 * (size_t)N_NODES * D2 * 4;
  int* deg     = (int*)intsBase;
  int* offsets = (int*)(intsBase + 200192);
  int* cursor  = (int*)(intsBase + 400384);
  int* ssrc    = (int*)(intsBase + 600576);                      // 1.8 MB
  unsigned short* wt = (unsigned short*)ws;  ws += (size_t)NB * DIM_IN * 2;  // 0.79 MB

  convx_kernel<<<2048, 256, 0, stream>>>(x, xb);
  convw_kernel<<<(NB * DIM_IN + 255) / 256, 256, 0, stream>>>(W1l, W1r, wt);
  gemm1_mfma<<<dim3((N_NODES + 127) / 128, NB / 128), 256, 0, stream>>>(xb, wt, xlr);
  // CSR build AFTER gemm1 (its buffers alias xb)
  init_deg_kernel<<<(N_NODES + 255) / 256, 256, 0, stream>>>(deg);
  hist_kernel<<<(N_EDGES + 255) / 256, 256, 0, stream>>>(edst, deg);
  scan_kernel<<<1, 1024, 0, stream>>>(deg, offsets, cursor);
  scatter_kernel<<<(E_TOT + 255) / 256, 256, 0, stream>>>(esrc, edst, cursor, ssrc);
  layer1_kernel<<<(N_NODES * 64 + 255) / 256, 256, 0, stream>>>(xlr, offsets, ssrc, att1, b1, h);
  gemm2_kernel<<<N_NODES / 16, 256, 0, stream>>>(h, W2l, W2r, xl2, xr2);
  layer2_kernel<<<(N_NODES * D2 + 255) / 256, 256, 0, stream>>>(xl2, xr2, offsets, ssrc, att2, b2, out);
}

// Round 7
// 548.053 us; speedup vs baseline: 1.6706x; 1.0161x over previous
//
#include <hip/hip_runtime.h>
#include <math.h>

#define N_NODES 50000
#define N_EDGES 400000
#define E_TOT   450000     // edges + self loops
#define DIM_IN  768
#define HC      256        // heads * dim_h = 8*32
#define D2      16
#define NB      512        // gemm1 output cols (xl | xr)

typedef __attribute__((ext_vector_type(8))) short short8v;   // 8 bf16 (4 VGPR)
typedef __attribute__((ext_vector_type(4))) float f32x4;     // MFMA acc

__device__ __forceinline__ float lrelu(float x) { return x > 0.f ? x : 0.2f * x; }

// fp32 -> bf16 round-to-nearest-even
__device__ __forceinline__ unsigned short f2bf(float f) {
  unsigned int u = __float_as_uint(f);
  unsigned int r = u + 0x7fffu + ((u >> 16) & 1u);
  return (unsigned short)(r >> 16);
}
__device__ __forceinline__ float bf2f(unsigned short u) {
  return __uint_as_float(((unsigned int)u) << 16);
}

// ---------------- convert x to bf16 ---------------------------------------
__global__ __launch_bounds__(256) void convx_kernel(
    const float* __restrict__ x, unsigned short* __restrict__ xb) {
  const int ntask = (N_NODES * DIM_IN) / 8;   // 4.8M tasks of 8 elems
  const int stride = gridDim.x * blockDim.x;
  for (int i = blockIdx.x * blockDim.x + threadIdx.x; i < ntask; i += stride) {
    const float4 a = ((const float4*)x)[2 * (size_t)i];
    const float4 b = ((const float4*)x)[2 * (size_t)i + 1];
    short8v v;
    v[0] = (short)f2bf(a.x); v[1] = (short)f2bf(a.y);
    v[2] = (short)f2bf(a.z); v[3] = (short)f2bf(a.w);
    v[4] = (short)f2bf(b.x); v[5] = (short)f2bf(b.y);
    v[6] = (short)f2bf(b.z); v[7] = (short)f2bf(b.w);
    ((short8v*)xb)[i] = v;
  }
}

// ---------------- build WcatT[512][768] = [W1l | W1r]^T in bf16 -----------
__global__ __launch_bounds__(256) void convw_kernel(
    const float* __restrict__ W1l, const float* __restrict__ W1r,
    unsigned short* __restrict__ wt) {
  const int idx = blockIdx.x * 256 + threadIdx.x;
  if (idx >= NB * DIM_IN) return;
  const int n = idx / DIM_IN, k = idx - n * DIM_IN;
  const float v = (n < HC) ? W1l[(size_t)k * HC + n] : W1r[(size_t)k * HC + (n - HC)];
  wt[idx] = f2bf(v);  // writes coalesced along k
}

// ---------------- GEMM1 (bf16 MFMA): [xl|xr] = x @ [W1l|W1r] ---------------
// 128x128 tile, BK=64, 4 waves (2x2), global_load_lds staging with
// pre-swizzled global source + XOR-swizzled ds_read (linear LDS dest).
// Epilogue: xl half (bn0<256) -> compact bf16 xlb[.][256]; xr half -> fp32.
__global__ __launch_bounds__(256) void gemm1_mfma(
    const unsigned short* __restrict__ xb, const unsigned short* __restrict__ wt,
    unsigned short* __restrict__ xlb, float* __restrict__ xrA) {
  __shared__ unsigned short Al[128 * 64];   // 16 KB, rows of 64 bf16 (128 B)
  __shared__ unsigned short Bl[128 * 64];   // 16 KB, rows = output cols
  const int t = threadIdx.x;
  const int lane = t & 63;
  const int w = t >> 6;            // wave 0..3
  const int wr = w >> 1, wc = w & 1;
  const int bm0 = blockIdx.x * 128;
  const int bn0 = blockIdx.y * 128;

  // staging geometry: wave handles rowgroups rg = w*4+q (8 rows x 128 B each)
  const int r8 = lane >> 3;                         // row within group 0..7
  const int swz_cb = ((lane & 7) << 4) ^ (r8 << 4); // pre-swizzled source col byte

  f32x4 acc[4][4];
#pragma unroll
  for (int m = 0; m < 4; ++m)
#pragma unroll
    for (int n = 0; n < 4; ++n) acc[m][n] = (f32x4)0.f;

  const int fr = lane & 15;     // frag row/col
  const int kg = lane >> 4;     // k-group 0..3
  const int swr = (fr & 7) << 4;

  for (int k0 = 0; k0 < DIM_IN; k0 += 64) {
    __syncthreads();   // previous compute finished before overwrite
#pragma unroll
    for (int q = 0; q < 4; ++q) {
      const int rg = w * 4 + q;
      int grow = bm0 + rg * 8 + r8;
      grow = grow < N_NODES ? grow : N_NODES - 1;   // clamp (dup rows, stores guarded)
      const char* src = (const char*)(xb + (size_t)grow * DIM_IN + k0) + swz_cb;
      __builtin_amdgcn_global_load_lds(
          (const __attribute__((address_space(1))) void*)src,
          (__attribute__((address_space(3))) void*)((char*)Al + rg * 1024), 16, 0, 0);
    }
#pragma unroll
    for (int q = 0; q < 4; ++q) {
      const int rg = w * 4 + q;
      const int brow = bn0 + rg * 8 + r8;
      const char* src = (const char*)(wt + (size_t)brow * DIM_IN + k0) + swz_cb;
      __builtin_amdgcn_global_load_lds(
          (const __attribute__((address_space(1))) void*)src,
          (__attribute__((address_space(3))) void*)((char*)Bl + rg * 1024), 16, 0, 0);
    }
    __syncthreads();   // staged tile visible (barrier drains vmcnt)

    short8v af[4][2], bf[4][2];
#pragma unroll
    for (int m = 0; m < 4; ++m) {
      const int row = wr * 64 + m * 16 + fr;
#pragma unroll
      for (int ks = 0; ks < 2; ++ks) {
        const int cb = (ks * 64 + kg * 16) ^ swr;
        af[m][ks] = *(const short8v*)((const char*)Al + row * 128 + cb);
      }
    }
#pragma unroll
    for (int n = 0; n < 4; ++n) {
      const int row = wc * 64 + n * 16 + fr;
#pragma unroll
      for (int ks = 0; ks < 2; ++ks) {
        const int cb = (ks * 64 + kg * 16) ^ swr;
        bf[n][ks] = *(const short8v*)((const char*)Bl + row * 128 + cb);
      }
    }
#pragma unroll
    for (int ks = 0; ks < 2; ++ks)
#pragma unroll
      for (int m = 0; m < 4; ++m)
#pragma unroll
        for (int n = 0; n < 4; ++n)
          acc[m][n] = __builtin_amdgcn_mfma_f32_16x16x32_bf16(
              af[m][ks], bf[n][ks], acc[m][n], 0, 0, 0);
  }

  // epilogue: C/D map col=lane&15, row=(lane>>4)*4+reg  [m89/m91 verified]
  const bool isXl = (bn0 < HC);
#pragma unroll
  for (int m = 0; m < 4; ++m) {
    const int grow_base = bm0 + wr * 64 + m * 16 + kg * 4;
#pragma unroll
    for (int n = 0; n < 4; ++n) {
      const int gcol = bn0 + wc * 64 + n * 16 + fr;
#pragma unroll
      for (int r = 0; r < 4; ++r) {
        const int grow = grow_base + r;
        if (grow < N_NODES) {
          if (isXl) xlb[(size_t)grow * HC + gcol] = f2bf(acc[m][n][r]);
          else      xrA[(size_t)grow * HC + (gcol - HC)] = acc[m][n][r];
        }
      }
    }
  }
}

// ---------------- CSR build ------------------------------------------------
__global__ void init_deg_kernel(int* __restrict__ deg) {
  int i = blockIdx.x * blockDim.x + threadIdx.x;
  if (i < N_NODES) deg[i] = 1;   // self loop
}

__global__ void hist_kernel(const int* __restrict__ dst, int* __restrict__ deg) {
  int e = blockIdx.x * blockDim.x + threadIdx.x;
  if (e < N_EDGES) atomicAdd(&deg[dst[e]], 1);
}

__global__ __launch_bounds__(1024) void scan_kernel(
    const int* __restrict__ deg, int* __restrict__ offsets, int* __restrict__ cursor) {
  __shared__ int wsum[16];
  __shared__ int wpre[16];
  __shared__ int scarry;
  const int t = threadIdx.x, lane = t & 63, wid = t >> 6;
  if (t == 0) scarry = 0;
  __syncthreads();
  for (int base = 0; base < N_NODES; base += 1024) {
    const int idx = base + t;
    const int v = (idx < N_NODES) ? deg[idx] : 0;
    int inc = v;
#pragma unroll
    for (int d = 1; d < 64; d <<= 1) {
      int n = __shfl_up(inc, d);
      if (lane >= d) inc += n;
    }
    if (lane == 63) wsum[wid] = inc;
    __syncthreads();
    if (t < 16) {
      int wv = wsum[t];
      int winc = wv;
#pragma unroll
      for (int d = 1; d < 16; d <<= 1) {
        int n = __shfl_up(winc, d);
        if (t >= d) winc += n;
      }
      wpre[t] = winc - wv;          // exclusive wave prefix
      if (t == 15) wsum[15] = winc; // chunk total
    }
    __syncthreads();
    const int excl = scarry + wpre[wid] + inc - v;
    if (idx < N_NODES) { offsets[idx] = excl; cursor[idx] = excl; }
    __syncthreads();
    if (t == 15) scarry += wsum[15];
    __syncthreads();
  }
  if (t == 0) offsets[N_NODES] = scarry;
}

__global__ void scatter_kernel(const int* __restrict__ src, const int* __restrict__ dst,
                               int* __restrict__ cursor, int* __restrict__ ssrc) {
  int e = blockIdx.x * blockDim.x + threadIdx.x;
  if (e >= E_TOT) return;
  int d, s;
  if (e < N_EDGES) { d = dst[e]; s = src[e]; }
  else { d = e - N_EDGES; s = d; }
  int pos = atomicAdd(&cursor[d], 1);
  ssrc[pos] = s;
}

// ---------------- Layer 1: one wave per node, online softmax --------------
// xl is bf16 compact [N][256] (25.6 MB, ~L2-resident); xr fp32, read 1x/node.
__global__ __launch_bounds__(256) void layer1_kernel(
    const unsigned short* __restrict__ xlb, const float* __restrict__ xrA,
    const int* __restrict__ offsets, const int* __restrict__ ssrc,
    const float* __restrict__ att1, const float* __restrict__ b1,
    float* __restrict__ h) {
  const int wid = (blockIdx.x * blockDim.x + threadIdx.x) >> 6;
  const int lane = threadIdx.x & 63;
  if (wid >= N_NODES) return;
  const int i = wid;
  const int lane4 = lane << 2;
  const float4 xr = *(const float4*)(xrA + (size_t)i * HC + lane4);
  const float4 av = *(const float4*)(att1 + lane4);
  const int e0 = offsets[i], e1 = offsets[i + 1];
  float m = -INFINITY, s = 0.f;
  float acc0 = 0.f, acc1 = 0.f, acc2 = 0.f, acc3 = 0.f;
  // software pipeline: current row in vc, next row load issued before the
  // exp/shfl chain of the current edge.
  ushort4 vc = *(const ushort4*)(xlb + (size_t)ssrc[e0] * HC + lane4);
  for (int e = e0; e < e1; ++e) {
    const int jn = (e + 1 < e1) ? ssrc[e + 1] : 0;
    const ushort4 vn = *(const ushort4*)(xlb + (size_t)jn * HC + lane4);
    const float v0 = bf2f(vc.x), v1 = bf2f(vc.y), v2 = bf2f(vc.z), v3 = bf2f(vc.w);
    float p = lrelu(v0 + xr.x) * av.x + lrelu(v1 + xr.y) * av.y +
              lrelu(v2 + xr.z) * av.z + lrelu(v3 + xr.w) * av.w;
    p += __shfl_xor(p, 1);
    p += __shfl_xor(p, 2);
    p += __shfl_xor(p, 4);     // per-head score, replicated in 8-lane group
    if (p > m) {
      const float f = __expf(m - p);   // m==-inf -> 0
      s *= f; acc0 *= f; acc1 *= f; acc2 *= f; acc3 *= f;
      m = p;
    }
    const float w = __expf(p - m);
    s += w;
    acc0 += w * v0; acc1 += w * v1; acc2 += w * v2; acc3 += w * v3;
    vc = vn;
  }
  const float inv = 1.f / s;
  float r0 = acc0 * inv + b1[lane4 + 0];
  float r1 = acc1 * inv + b1[lane4 + 1];
  float r2 = acc2 * inv + b1[lane4 + 2];
  float r3 = acc3 * inv + b1[lane4 + 3];
  // ELU
  r0 = r0 > 0.f ? r0 : __expf(r0) - 1.f;
  r1 = r1 > 0.f ? r1 : __expf(r1) - 1.f;
  r2 = r2 > 0.f ? r2 : __expf(r2) - 1.f;
  r3 = r3 > 0.f ? r3 : __expf(r3) - 1.f;
  *(float4*)(h + (size_t)i * HC + lane4) = make_float4(r0, r1, r2, r3);
}

// ---------------- GEMM2: xl2 = h@W2l, xr2 = h@W2r (K=256 -> 16) -----------
__global__ __launch_bounds__(256) void gemm2_kernel(
    const float* __restrict__ h, const float* __restrict__ W2l,
    const float* __restrict__ W2r, float* __restrict__ xl2, float* __restrict__ xr2) {
  __shared__ float Wl[HC * D2];
  __shared__ float Wr[HC * D2];
  __shared__ float hrow[16 * (HC + 4)];   // padded rows: no 4-way bank conflict
  const int t = threadIdx.x;
  for (int idx = t; idx < HC * D2; idx += 256) { Wl[idx] = W2l[idx]; Wr[idx] = W2r[idx]; }
  const int nodeBase = blockIdx.x * 16;
  for (int idx = t; idx < 16 * HC; idx += 256) {
    const int r = idx >> 8, c = idx & 255;
    hrow[r * (HC + 4) + c] = h[(size_t)nodeBase * HC + idx];
  }
  __syncthreads();
  const int ln = t >> 4;
  const int c = t & 15;
  const float* hp = hrow + ln * (HC + 4);
  float al = 0.f, ar = 0.f;
#pragma unroll 8
  for (int k = 0; k < HC; ++k) {
    const float hv = hp[k];
    al += hv * Wl[k * D2 + c];
    ar += hv * Wr[k * D2 + c];
  }
  const int node = nodeBase + ln;
  xl2[node * D2 + c] = al;
  xr2[node * D2 + c] = ar;
}

// ---------------- Layer 2 + log_softmax: 16 lanes per node ----------------
__global__ __launch_bounds__(256) void layer2_kernel(
    const float* __restrict__ xl2, const float* __restrict__ xr2,
    const int* __restrict__ offsets, const int* __restrict__ ssrc,
    const float* __restrict__ att2, const float* __restrict__ b2,
    float* __restrict__ out) {
  const int gtid = blockIdx.x * blockDim.x + threadIdx.x;
  const int node = gtid >> 4;
  const int c = gtid & 15;
  if (node >= N_NODES) return;
  const float xr = xr2[node * D2 + c];
  const float av = att2[c];
  const int e0 = offsets[node], e1 = offsets[node + 1];
  float m = -INFINITY, s = 0.f, acc = 0.f;
  for (int e = e0; e < e1; ++e) {
    const int j = ssrc[e];
    const float v = xl2[j * D2 + c];
    float p = lrelu(v + xr) * av;
    p += __shfl_xor(p, 1);
    p += __shfl_xor(p, 2);
    p += __shfl_xor(p, 4);
    p += __shfl_xor(p, 8);     // score for this node, replicated in 16-lane group
    if (p > m) {
      const float f = __expf(m - p);
      s *= f; acc *= f;
      m = p;
    }
    const float w = __expf(p - m);
    s += w;
    acc += w * v;
  }
  const float o = acc / s + b2[c];
  out[(size_t)node * D2 + c] = o;
  // log_softmax over the 16 channels of this node
  float mx = o;
#pragma unroll
  for (int d = 1; d < 16; d <<= 1) mx = fmaxf(mx, __shfl_xor(mx, d));
  float ex = __expf(o - mx);
  float sum = ex;
#pragma unroll
  for (int d = 1; d < 16; d <<= 1) sum += __shfl_xor(sum, d);
  out[(size_t)N_NODES * D2 + (size_t)node * D2 + c] = o - mx - __logf(sum);
}

// ---------------- launch ---------------------------------------------------
extern "C" void kernel_launch(void* const* d_in, const int* in_sizes, int n_in,
                              void* d_out, int out_size, void* d_ws, size_t ws_size,
                              hipStream_t stream) {
  const float* x    = (const float*)d_in[0];
  const int*   ei   = (const int*)d_in[1];
  const float* W1l  = (const float*)d_in[2];
  const float* W1r  = (const float*)d_in[3];
  const float* att1 = (const float*)d_in[4];
  const float* b1   = (const float*)d_in[5];
  const float* W2l  = (const float*)d_in[6];
  const float* W2r  = (const float*)d_in[7];
  const float* att2 = (const float*)d_in[8];
  const float* b2   = (const float*)d_in[9];
  const int* esrc = ei;
  const int* edst = ei + N_EDGES;
  float* out = (float*)d_out;

  char* ws = (char*)d_ws;
  unsigned short* xlb = (unsigned short*)ws;  ws += (size_t)N_NODES * HC * 2;  // 25.6 MB
  float* xrA = (float*)ws;                    ws += (size_t)N_NODES * HC * 4;  // 51.2 MB
  // union region: xb (bf16 x) lives only until gemm1; everything below it
  // is written strictly after gemm1 completes (stream-serial order below).
  char* region = ws;                          ws += (size_t)N_NODES * DIM_IN * 2; // 76.8 MB
  unsigned short* xb = (unsigned short*)region;
  float* h   = (float*)region;                                   // 51.2 MB
  float* xl2 = (float*)(region + (size_t)N_NODES * HC * 4);      //  3.2 MB
  float* xr2 = (float*)(region + (size_t)N_NODES * HC * 4 + (size_t)N_NODES * D2 * 4);
  char* intsBase = region + (size_t)N_NODES * HC * 4 + 2 * (size_t)N_NODES * D2 * 4;
  int* deg     = (int*)intsBase;
  int* offsets = (int*)(intsBase + 200192);
  int* cursor  = (int*)(intsBase + 400384);
  int* ssrc    = (int*)(intsBase + 600576);                      // 1.8 MB
  unsigned short* wt = (unsigned short*)ws;   ws += (size_t)NB * DIM_IN * 2;   // 0.79 MB

  convx_kernel<<<2048, 256, 0, stream>>>(x, xb);
  convw_kernel<<<(NB * DIM_IN + 255) / 256, 256, 0, stream>>>(W1l, W1r, wt);
  gemm1_mfma<<<dim3((N_NODES + 127) / 128, NB / 128), 256, 0, stream>>>(xb, wt, xlb, xrA);
  // CSR build AFTER gemm1 (its buffers alias xb)
  init_deg_kernel<<<(N_NODES + 255) / 256, 256, 0, stream>>>(deg);
  hist_kernel<<<(N_EDGES + 255) / 256, 256, 0, stream>>>(edst, deg);
  scan_kernel<<<1, 1024, 0, stream>>>(deg, offsets, cursor);
  scatter_kernel<<<(E_TOT + 255) / 256, 256, 0, stream>>>(esrc, edst, cursor, ssrc);
  layer1_kernel<<<(N_NODES * 64 + 255) / 256, 256, 0, stream>>>(xlb, xrA, offsets, ssrc, att1, b1, h);
  gemm2_kernel<<<N_NODES / 16, 256, 0, stream>>>(h, W2l, W2r, xl2, xr2);
  layer2_kernel<<<(N_NODES * D2 + 255) / 256, 256, 0, stream>>>(xl2, xr2, offsets, ssrc, att2, b2, out);
}

// Round 11
// 543.219 us; speedup vs baseline: 1.6855x; 1.0089x over previous
//
#include <hip/hip_runtime.h>
#include <math.h>

#define N_NODES 50000
#define N_EDGES 400000
#define E_TOT   450000     // edges + self loops
#define DIM_IN  768
#define HC      256        // heads * dim_h = 8*32
#define D2      16
#define NB      512        // gemm1 output cols (xl | xr)
#define NKT     12         // K-tiles: 768 / 64

typedef __attribute__((ext_vector_type(8))) short short8v;   // 8 bf16 (4 VGPR)
typedef __attribute__((ext_vector_type(4))) float f32x4;     // MFMA acc

__device__ __forceinline__ float lrelu(float x) { return x > 0.f ? x : 0.2f * x; }

// fp32 -> bf16 round-to-nearest-even
__device__ __forceinline__ unsigned short f2bf(float f) {
  unsigned int u = __float_as_uint(f);
  unsigned int r = u + 0x7fffu + ((u >> 16) & 1u);
  return (unsigned short)(r >> 16);
}
__device__ __forceinline__ float bf2f(unsigned short u) {
  return __uint_as_float(((unsigned int)u) << 16);
}

// ---------------- convert x to bf16 ---------------------------------------
__global__ __launch_bounds__(256) void convx_kernel(
    const float* __restrict__ x, unsigned short* __restrict__ xb) {
  const int ntask = (N_NODES * DIM_IN) / 8;   // 4.8M tasks of 8 elems
  const int stride = gridDim.x * blockDim.x;
  for (int i = blockIdx.x * blockDim.x + threadIdx.x; i < ntask; i += stride) {
    const float4 a = ((const float4*)x)[2 * (size_t)i];
    const float4 b = ((const float4*)x)[2 * (size_t)i + 1];
    short8v v;
    v[0] = (short)f2bf(a.x); v[1] = (short)f2bf(a.y);
    v[2] = (short)f2bf(a.z); v[3] = (short)f2bf(a.w);
    v[4] = (short)f2bf(b.x); v[5] = (short)f2bf(b.y);
    v[6] = (short)f2bf(b.z); v[7] = (short)f2bf(b.w);
    ((short8v*)xb)[i] = v;
  }
}

// ---------------- build WcatT[512][768] = [W1l | W1r]^T in bf16 -----------
__global__ __launch_bounds__(256) void convw_kernel(
    const float* __restrict__ W1l, const float* __restrict__ W1r,
    unsigned short* __restrict__ wt) {
  const int idx = blockIdx.x * 256 + threadIdx.x;
  if (idx >= NB * DIM_IN) return;
  const int n = idx / DIM_IN, k = idx - n * DIM_IN;
  const float v = (n < HC) ? W1l[(size_t)k * HC + n] : W1r[(size_t)k * HC + (n - HC)];
  wt[idx] = f2bf(v);  // writes coalesced along k
}

// ---------------- GEMM1 (bf16 MFMA): [xl|xr] = x @ [W1l|W1r] ---------------
// 128x128 tile, BK=64, 4 waves (2x2). 2-phase double-buffered LDS (T3-min):
// STAGE(t+1) issued BEFORE compute(t); ONE barrier per K-step (its implicit
// vmcnt(0) drain lands after ds_read+MFMA, overlapping stage latency).
// global_load_lds w=16 with pre-swizzled source + XOR-swizzled ds_read.
__global__ __launch_bounds__(256) void gemm1_mfma(
    const unsigned short* __restrict__ xb, const unsigned short* __restrict__ wt,
    unsigned short* __restrict__ xlb, float* __restrict__ xrA) {
  __shared__ unsigned short Al[2][128 * 64];   // 2 x 16 KB
  __shared__ unsigned short Bl[2][128 * 64];   // 2 x 16 KB
  const int t = threadIdx.x;
  const int lane = t & 63;
  const int w = t >> 6;            // wave 0..3
  const int wr = w >> 1, wc = w & 1;
  const int bm0 = blockIdx.x * 128;
  const int bn0 = blockIdx.y * 128;

  // staging geometry: wave handles rowgroups rg = w*4+q (8 rows x 128 B each)
  const int r8 = lane >> 3;                         // row within group 0..7
  const int swz_cb = ((lane & 7) << 4) ^ (r8 << 4); // pre-swizzled source col byte

  f32x4 acc[4][4];
#pragma unroll
  for (int m = 0; m < 4; ++m)
#pragma unroll
    for (int n = 0; n < 4; ++n) acc[m][n] = (f32x4)0.f;

  const int fr = lane & 15;     // frag row/col
  const int kg = lane >> 4;     // k-group 0..3
  const int swr = (fr & 7) << 4;

  auto stage = [&](int buf, int k0) {
#pragma unroll
    for (int q = 0; q < 4; ++q) {
      const int rg = w * 4 + q;
      int grow = bm0 + rg * 8 + r8;
      grow = grow < N_NODES ? grow : N_NODES - 1;   // clamp (dup rows, stores guarded)
      const char* src = (const char*)(xb + (size_t)grow * DIM_IN + k0) + swz_cb;
      __builtin_amdgcn_global_load_lds(
          (const __attribute__((address_space(1))) void*)src,
          (__attribute__((address_space(3))) void*)((char*)Al + buf * 16384 + rg * 1024),
          16, 0, 0);
    }
#pragma unroll
    for (int q = 0; q < 4; ++q) {
      const int rg = w * 4 + q;
      const int brow = bn0 + rg * 8 + r8;
      const char* src = (const char*)(wt + (size_t)brow * DIM_IN + k0) + swz_cb;
      __builtin_amdgcn_global_load_lds(
          (const __attribute__((address_space(1))) void*)src,
          (__attribute__((address_space(3))) void*)((char*)Bl + buf * 16384 + rg * 1024),
          16, 0, 0);
    }
  };

  // prologue: stage tile 0, wait, barrier
  stage(0, 0);
  __syncthreads();   // compiler drains vmcnt(0) here -> tile 0 visible

  int cur = 0;
  for (int kt = 0; kt < NKT; ++kt) {
    if (kt + 1 < NKT) stage(cur ^ 1, (kt + 1) * 64);   // issue next tile FIRST

    const char* Ab = (const char*)Al + cur * 16384;
    const char* Bb = (const char*)Bl + cur * 16384;
    short8v af[4][2], bf[4][2];
#pragma unroll
    for (int m = 0; m < 4; ++m) {
      const int row = wr * 64 + m * 16 + fr;
#pragma unroll
      for (int ks = 0; ks < 2; ++ks) {
        const int cb = (ks * 64 + kg * 16) ^ swr;
        af[m][ks] = *(const short8v*)(Ab + row * 128 + cb);
      }
    }
#pragma unroll
    for (int n = 0; n < 4; ++n) {
      const int row = wc * 64 + n * 16 + fr;
#pragma unroll
      for (int ks = 0; ks < 2; ++ks) {
        const int cb = (ks * 64 + kg * 16) ^ swr;
        bf[n][ks] = *(const short8v*)(Bb + row * 128 + cb);
      }
    }
#pragma unroll
    for (int ks = 0; ks < 2; ++ks)
#pragma unroll
      for (int m = 0; m < 4; ++m)
#pragma unroll
        for (int n = 0; n < 4; ++n)
          acc[m][n] = __builtin_amdgcn_mfma_f32_16x16x32_bf16(
              af[m][ks], bf[n][ks], acc[m][n], 0, 0, 0);

    if (kt + 1 < NKT) {
      __syncthreads();   // drains vmcnt(0): next tile ready; cur safe to reuse
      cur ^= 1;
    }
  }

  // epilogue: C/D map col=lane&15, row=(lane>>4)*4+reg  [m89/m91 verified]
  const bool isXl = (bn0 < HC);
#pragma unroll
  for (int m = 0; m < 4; ++m) {
    const int grow_base = bm0 + wr * 64 + m * 16 + kg * 4;
#pragma unroll
    for (int n = 0; n < 4; ++n) {
      const int gcol = bn0 + wc * 64 + n * 16 + fr;
#pragma unroll
      for (int r = 0; r < 4; ++r) {
        const int grow = grow_base + r;
        if (grow < N_NODES) {
          if (isXl) xlb[(size_t)grow * HC + gcol] = f2bf(acc[m][n][r]);
          else      xrA[(size_t)grow * HC + (gcol - HC)] = acc[m][n][r];
        }
      }
    }
  }
}

// ---------------- CSR build ------------------------------------------------
__global__ void init_deg_kernel(int* __restrict__ deg) {
  int i = blockIdx.x * blockDim.x + threadIdx.x;
  if (i < N_NODES) deg[i] = 1;   // self loop
}

__global__ void hist_kernel(const int* __restrict__ dst, int* __restrict__ deg) {
  int e = blockIdx.x * blockDim.x + threadIdx.x;
  if (e < N_EDGES) atomicAdd(&deg[dst[e]], 1);
}

__global__ __launch_bounds__(1024) void scan_kernel(
    const int* __restrict__ deg, int* __restrict__ offsets, int* __restrict__ cursor) {
  __shared__ int wsum[16];
  __shared__ int wpre[16];
  __shared__ int scarry;
  const int t = threadIdx.x, lane = t & 63, wid = t >> 6;
  if (t == 0) scarry = 0;
  __syncthreads();
  for (int base = 0; base < N_NODES; base += 1024) {
    const int idx = base + t;
    const int v = (idx < N_NODES) ? deg[idx] : 0;
    int inc = v;
#pragma unroll
    for (int d = 1; d < 64; d <<= 1) {
      int n = __shfl_up(inc, d);
      if (lane >= d) inc += n;
    }
    if (lane == 63) wsum[wid] = inc;
    __syncthreads();
    if (t < 16) {
      int wv = wsum[t];
      int winc = wv;
#pragma unroll
      for (int d = 1; d < 16; d <<= 1) {
        int n = __shfl_up(winc, d);
        if (t >= d) winc += n;
      }
      wpre[t] = winc - wv;          // exclusive wave prefix
      if (t == 15) wsum[15] = winc; // chunk total
    }
    __syncthreads();
    const int excl = scarry + wpre[wid] + inc - v;
    if (idx < N_NODES) { offsets[idx] = excl; cursor[idx] = excl; }
    __syncthreads();
    if (t == 15) scarry += wsum[15];
    __syncthreads();
  }
  if (t == 0) offsets[N_NODES] = scarry;
}

__global__ void scatter_kernel(const int* __restrict__ src, const int* __restrict__ dst,
                               int* __restrict__ cursor, int* __restrict__ ssrc) {
  int e = blockIdx.x * blockDim.x + threadIdx.x;
  if (e >= E_TOT) return;
  int d, s;
  if (e < N_EDGES) { d = dst[e]; s = src[e]; }
  else { d = e - N_EDGES; s = d; }
  int pos = atomicAdd(&cursor[d], 1);
  ssrc[pos] = s;
}

// ---------------- Layer 1: one wave per node, online softmax --------------
// xl is bf16 compact [N][256] (25.6 MB, ~L2-resident); xr fp32, read 1x/node.
__global__ __launch_bounds__(256) void layer1_kernel(
    const unsigned short* __restrict__ xlb, const float* __restrict__ xrA,
    const int* __restrict__ offsets, const int* __restrict__ ssrc,
    const float* __restrict__ att1, const float* __restrict__ b1,
    float* __restrict__ h) {
  const int wid = (blockIdx.x * blockDim.x + threadIdx.x) >> 6;
  const int lane = threadIdx.x & 63;
  if (wid >= N_NODES) return;
  const int i = wid;
  const int lane4 = lane << 2;
  const float4 xr = *(const float4*)(xrA + (size_t)i * HC + lane4);
  const float4 av = *(const float4*)(att1 + lane4);
  const int e0 = offsets[i], e1 = offsets[i + 1];
  float m = -INFINITY, s = 0.f;
  float acc0 = 0.f, acc1 = 0.f, acc2 = 0.f, acc3 = 0.f;
  // software pipeline: current row in vc, next row load issued before the
  // exp/shfl chain of the current edge.
  ushort4 vc = *(const ushort4*)(xlb + (size_t)ssrc[e0] * HC + lane4);
  for (int e = e0; e < e1; ++e) {
    const int jn = (e + 1 < e1) ? ssrc[e + 1] : 0;
    const ushort4 vn = *(const ushort4*)(xlb + (size_t)jn * HC + lane4);
    const float v0 = bf2f(vc.x), v1 = bf2f(vc.y), v2 = bf2f(vc.z), v3 = bf2f(vc.w);
    float p = lrelu(v0 + xr.x) * av.x + lrelu(v1 + xr.y) * av.y +
              lrelu(v2 + xr.z) * av.z + lrelu(v3 + xr.w) * av.w;
    p += __shfl_xor(p, 1);
    p += __shfl_xor(p, 2);
    p += __shfl_xor(p, 4);     // per-head score, replicated in 8-lane group
    if (p > m) {
      const float f = __expf(m - p);   // m==-inf -> 0
      s *= f; acc0 *= f; acc1 *= f; acc2 *= f; acc3 *= f;
      m = p;
    }
    const float w = __expf(p - m);
    s += w;
    acc0 += w * v0; acc1 += w * v1; acc2 += w * v2; acc3 += w * v3;
    vc = vn;
  }
  const float inv = 1.f / s;
  float r0 = acc0 * inv + b1[lane4 + 0];
  float r1 = acc1 * inv + b1[lane4 + 1];
  float r2 = acc2 * inv + b1[lane4 + 2];
  float r3 = acc3 * inv + b1[lane4 + 3];
  // ELU
  r0 = r0 > 0.f ? r0 : __expf(r0) - 1.f;
  r1 = r1 > 0.f ? r1 : __expf(r1) - 1.f;
  r2 = r2 > 0.f ? r2 : __expf(r2) - 1.f;
  r3 = r3 > 0.f ? r3 : __expf(r3) - 1.f;
  *(float4*)(h + (size_t)i * HC + lane4) = make_float4(r0, r1, r2, r3);
}

// ---------------- GEMM2: xl2 = h@W2l, xr2 = h@W2r (K=256 -> 16) -----------
__global__ __launch_bounds__(256) void gemm2_kernel(
    const float* __restrict__ h, const float* __restrict__ W2l,
    const float* __restrict__ W2r, float* __restrict__ xl2, float* __restrict__ xr2) {
  __shared__ float Wl[HC * D2];
  __shared__ float Wr[HC * D2];
  __shared__ float hrow[16 * (HC + 4)];   // padded rows: no 4-way bank conflict
  const int t = threadIdx.x;
  for (int idx = t; idx < HC * D2; idx += 256) { Wl[idx] = W2l[idx]; Wr[idx] = W2r[idx]; }
  const int nodeBase = blockIdx.x * 16;
  for (int idx = t; idx < 16 * HC; idx += 256) {
    const int r = idx >> 8, c = idx & 255;
    hrow[r * (HC + 4) + c] = h[(size_t)nodeBase * HC + idx];
  }
  __syncthreads();
  const int ln = t >> 4;
  const int c = t & 15;
  const float* hp = hrow + ln * (HC + 4);
  float al = 0.f, ar = 0.f;
#pragma unroll 8
  for (int k = 0; k < HC; ++k) {
    const float hv = hp[k];
    al += hv * Wl[k * D2 + c];
    ar += hv * Wr[k * D2 + c];
  }
  const int node = nodeBase + ln;
  xl2[node * D2 + c] = al;
  xr2[node * D2 + c] = ar;
}

// ---------------- Layer 2 + log_softmax: 16 lanes per node ----------------
__global__ __launch_bounds__(256) void layer2_kernel(
    const float* __restrict__ xl2, const float* __restrict__ xr2,
    const int* __restrict__ offsets, const int* __restrict__ ssrc,
    const float* __restrict__ att2, const float* __restrict__ b2,
    float* __restrict__ out) {
  const int gtid = blockIdx.x * blockDim.x + threadIdx.x;
  const int node = gtid >> 4;
  const int c = gtid & 15;
  if (node >= N_NODES) return;
  const float xr = xr2[node * D2 + c];
  const float av = att2[c];
  const int e0 = offsets[node], e1 = offsets[node + 1];
  float m = -INFINITY, s = 0.f, acc = 0.f;
  for (int e = e0; e < e1; ++e) {
    const int j = ssrc[e];
    const float v = xl2[j * D2 + c];
    float p = lrelu(v + xr) * av;
    p += __shfl_xor(p, 1);
    p += __shfl_xor(p, 2);
    p += __shfl_xor(p, 4);
    p += __shfl_xor(p, 8);     // score for this node, replicated in 16-lane group
    if (p > m) {
      const float f = __expf(m - p);
      s *= f; acc *= f;
      m = p;
    }
    const float w = __expf(p - m);
    s += w;
    acc += w * v;
  }
  const float o = acc / s + b2[c];
  out[(size_t)node * D2 + c] = o;
  // log_softmax over the 16 channels of this node
  float mx = o;
#pragma unroll
  for (int d = 1; d < 16; d <<= 1) mx = fmaxf(mx, __shfl_xor(mx, d));
  float ex = __expf(o - mx);
  float sum = ex;
#pragma unroll
  for (int d = 1; d < 16; d <<= 1) sum += __shfl_xor(sum, d);
  out[(size_t)N_NODES * D2 + (size_t)node * D2 + c] = o - mx - __logf(sum);
}

// ---------------- launch ---------------------------------------------------
extern "C" void kernel_launch(void* const* d_in, const int* in_sizes, int n_in,
                              void* d_out, int out_size, void* d_ws, size_t ws_size,
                              hipStream_t stream) {
  const float* x    = (const float*)d_in[0];
  const int*   ei   = (const int*)d_in[1];
  const float* W1l  = (const float*)d_in[2];
  const float* W1r  = (const float*)d_in[3];
  const float* att1 = (const float*)d_in[4];
  const float* b1   = (const float*)d_in[5];
  const float* W2l  = (const float*)d_in[6];
  const float* W2r  = (const float*)d_in[7];
  const float* att2 = (const float*)d_in[8];
  const float* b2   = (const float*)d_in[9];
  const int* esrc = ei;
  const int* edst = ei + N_EDGES;
  float* out = (float*)d_out;

  char* ws = (char*)d_ws;
  unsigned short* xlb = (unsigned short*)ws;  ws += (size_t)N_NODES * HC * 2;  // 25.6 MB
  float* xrA = (float*)ws;                    ws += (size_t)N_NODES * HC * 4;  // 51.2 MB
  // union region: xb (bf16 x) lives only until gemm1; everything below it
  // is written strictly after gemm1 completes (stream-serial order below).
  char* region = ws;                          ws += (size_t)N_NODES * DIM_IN * 2; // 76.8 MB
  unsigned short* xb = (unsigned short*)region;
  float* h   = (float*)region;                                   // 51.2 MB
  float* xl2 = (float*)(region + (size_t)N_NODES * HC * 4);      //  3.2 MB
  float* xr2 = (float*)(region + (size_t)N_NODES * HC * 4 + (size_t)N_NODES * D2 * 4);
  char* intsBase = region + (size_t)N_NODES * HC * 4 + 2 * (size_t)N_NODES * D2 * 4;
  int* deg     = (int*)intsBase;
  int* offsets = (int*)(intsBase + 200192);
  int* cursor  = (int*)(intsBase + 400384);
  int* ssrc    = (int*)(intsBase + 600576);                      // 1.8 MB
  unsigned short* wt = (unsigned short*)ws;   ws += (size_t)NB * DIM_IN * 2;   // 0.79 MB

  convx_kernel<<<2048, 256, 0, stream>>>(x, xb);
  convw_kernel<<<(NB * DIM_IN + 255) / 256, 256, 0, stream>>>(W1l, W1r, wt);
  gemm1_mfma<<<dim3((N_NODES + 127) / 128, NB / 128), 256, 0, stream>>>(xb, wt, xlb, xrA);
  // CSR build AFTER gemm1 (its buffers alias xb)
  init_deg_kernel<<<(N_NODES + 255) / 256, 256, 0, stream>>>(deg);
  hist_kernel<<<(N_EDGES + 255) / 256, 256, 0, stream>>>(edst, deg);
  scan_kernel<<<1, 1024, 0, stream>>>(deg, offsets, cursor);
  scatter_kernel<<<(E_TOT + 255) / 256, 256, 0, stream>>>(esrc, edst, cursor, ssrc);
  layer1_kernel<<<(N_NODES * 64 + 255) / 256, 256, 0, stream>>>(xlb, xrA, offsets, ssrc, att1, b1, h);
  gemm2_kernel<<<N_NODES / 16, 256, 0, stream>>>(h, W2l, W2r, xl2, xr2);
  layer2_kernel<<<(N_NODES * D2 + 255) / 256, 256, 0, stream>>>(xl2, xr2, offsets, ssrc, att2, b2, out);
}

// Round 13
// 532.392 us; speedup vs baseline: 1.7198x; 1.0203x over previous
//
#include <hip/hip_runtime.h>
#include <math.h>

#define N_NODES 50000
#define N_EDGES 400000
#define E_TOT   450000     // edges + self loops
#define DIM_IN  768
#define HC      256        // heads * dim_h = 8*32
#define D2      16
#define NB      512        // gemm1 output cols (xl | xr)
#define NKT     12         // K-tiles: 768 / 64
#define SCAN_B  196        // scan blocks (<= CU count -> co-resident, lookback safe)

typedef __attribute__((ext_vector_type(8))) short short8v;   // 8 bf16 (4 VGPR)
typedef __attribute__((ext_vector_type(4))) float f32x4;     // MFMA acc

__device__ __forceinline__ float lrelu(float x) { return x > 0.f ? x : 0.2f * x; }

// fp32 -> bf16 round-to-nearest-even
__device__ __forceinline__ unsigned short f2bf(float f) {
  unsigned int u = __float_as_uint(f);
  unsigned int r = u + 0x7fffu + ((u >> 16) & 1u);
  return (unsigned short)(r >> 16);
}
__device__ __forceinline__ float bf2f(unsigned short u) {
  return __uint_as_float(((unsigned int)u) << 16);
}

// ---------------- fused: convert x to bf16 + build WcatT bf16 --------------
// blocks [0,1536): wt[512][768] = [W1l|W1r]^T ; blocks [1536,3584): x -> xb
__global__ __launch_bounds__(256) void convxw_kernel(
    const float* __restrict__ x, const float* __restrict__ W1l,
    const float* __restrict__ W1r, unsigned short* __restrict__ xb,
    unsigned short* __restrict__ wt) {
  const int bid = blockIdx.x;
  const int t = threadIdx.x;
  if (bid < 1536) {                       // 1536*256 == 512*768 exactly
    const int idx = bid * 256 + t;
    const int n = idx / DIM_IN, k = idx - n * DIM_IN;
    const float v = (n < HC) ? W1l[(size_t)k * HC + n] : W1r[(size_t)k * HC + (n - HC)];
    wt[idx] = f2bf(v);
  } else {
    const int ntask = (N_NODES * DIM_IN) / 8;
    const int stride = 2048 * 256;
    for (int i = (bid - 1536) * 256 + t; i < ntask; i += stride) {
      const float4 a = ((const float4*)x)[2 * (size_t)i];
      const float4 b = ((const float4*)x)[2 * (size_t)i + 1];
      short8v v;
      v[0] = (short)f2bf(a.x); v[1] = (short)f2bf(a.y);
      v[2] = (short)f2bf(a.z); v[3] = (short)f2bf(a.w);
      v[4] = (short)f2bf(b.x); v[5] = (short)f2bf(b.y);
      v[6] = (short)f2bf(b.z); v[7] = (short)f2bf(b.w);
      ((short8v*)xb)[i] = v;
    }
  }
}

// ---------------- GEMM1 (bf16 MFMA): [xl|xr] = x @ [W1l|W1r] ---------------
// UNCHANGED from round 11 (88.5 us, MfmaUtil 17%).
__global__ __launch_bounds__(256) void gemm1_mfma(
    const unsigned short* __restrict__ xb, const unsigned short* __restrict__ wt,
    unsigned short* __restrict__ xlb, float* __restrict__ xrA) {
  __shared__ unsigned short Al[2][128 * 64];   // 2 x 16 KB
  __shared__ unsigned short Bl[2][128 * 64];   // 2 x 16 KB
  const int t = threadIdx.x;
  const int lane = t & 63;
  const int w = t >> 6;            // wave 0..3
  const int wr = w >> 1, wc = w & 1;
  const int bm0 = blockIdx.x * 128;
  const int bn0 = blockIdx.y * 128;

  const int r8 = lane >> 3;                         // row within group 0..7
  const int swz_cb = ((lane & 7) << 4) ^ (r8 << 4); // pre-swizzled source col byte

  f32x4 acc[4][4];
#pragma unroll
  for (int m = 0; m < 4; ++m)
#pragma unroll
    for (int n = 0; n < 4; ++n) acc[m][n] = (f32x4)0.f;

  const int fr = lane & 15;     // frag row/col
  const int kg = lane >> 4;     // k-group 0..3
  const int swr = (fr & 7) << 4;

  auto stage = [&](int buf, int k0) {
#pragma unroll
    for (int q = 0; q < 4; ++q) {
      const int rg = w * 4 + q;
      int grow = bm0 + rg * 8 + r8;
      grow = grow < N_NODES ? grow : N_NODES - 1;   // clamp (dup rows, stores guarded)
      const char* src = (const char*)(xb + (size_t)grow * DIM_IN + k0) + swz_cb;
      __builtin_amdgcn_global_load_lds(
          (const __attribute__((address_space(1))) void*)src,
          (__attribute__((address_space(3))) void*)((char*)Al + buf * 16384 + rg * 1024),
          16, 0, 0);
    }
#pragma unroll
    for (int q = 0; q < 4; ++q) {
      const int rg = w * 4 + q;
      const int brow = bn0 + rg * 8 + r8;
      const char* src = (const char*)(wt + (size_t)brow * DIM_IN + k0) + swz_cb;
      __builtin_amdgcn_global_load_lds(
          (const __attribute__((address_space(1))) void*)src,
          (__attribute__((address_space(3))) void*)((char*)Bl + buf * 16384 + rg * 1024),
          16, 0, 0);
    }
  };

  stage(0, 0);
  __syncthreads();   // tile 0 visible

  int cur = 0;
  for (int kt = 0; kt < NKT; ++kt) {
    if (kt + 1 < NKT) stage(cur ^ 1, (kt + 1) * 64);   // issue next tile FIRST

    const char* Ab = (const char*)Al + cur * 16384;
    const char* Bb = (const char*)Bl + cur * 16384;
    short8v af[4][2], bf[4][2];
#pragma unroll
    for (int m = 0; m < 4; ++m) {
      const int row = wr * 64 + m * 16 + fr;
#pragma unroll
      for (int ks = 0; ks < 2; ++ks) {
        const int cb = (ks * 64 + kg * 16) ^ swr;
        af[m][ks] = *(const short8v*)(Ab + row * 128 + cb);
      }
    }
#pragma unroll
    for (int n = 0; n < 4; ++n) {
      const int row = wc * 64 + n * 16 + fr;
#pragma unroll
      for (int ks = 0; ks < 2; ++ks) {
        const int cb = (ks * 64 + kg * 16) ^ swr;
        bf[n][ks] = *(const short8v*)(Bb + row * 128 + cb);
      }
    }
#pragma unroll
    for (int ks = 0; ks < 2; ++ks)
#pragma unroll
      for (int m = 0; m < 4; ++m)
#pragma unroll
        for (int n = 0; n < 4; ++n)
          acc[m][n] = __builtin_amdgcn_mfma_f32_16x16x32_bf16(
              af[m][ks], bf[n][ks], acc[m][n], 0, 0, 0);

    if (kt + 1 < NKT) {
      __syncthreads();
      cur ^= 1;
    }
  }

  const bool isXl = (bn0 < HC);
#pragma unroll
  for (int m = 0; m < 4; ++m) {
    const int grow_base = bm0 + wr * 64 + m * 16 + kg * 4;
#pragma unroll
    for (int n = 0; n < 4; ++n) {
      const int gcol = bn0 + wc * 64 + n * 16 + fr;
#pragma unroll
      for (int r = 0; r < 4; ++r) {
        const int grow = grow_base + r;
        if (grow < N_NODES) {
          if (isXl) xlb[(size_t)grow * HC + gcol] = f2bf(acc[m][n][r]);
          else      xrA[(size_t)grow * HC + (gcol - HC)] = acc[m][n][r];
        }
      }
    }
  }
}

// ---------------- CSR build ------------------------------------------------
__global__ void init_deg_kernel(int* __restrict__ deg, int* __restrict__ blocksum) {
  int i = blockIdx.x * blockDim.x + threadIdx.x;
  if (i < N_NODES) deg[i] = 1;   // self loop
  if (i < SCAN_B) blocksum[i] = -1;   // lookback sentinel
}

__global__ void hist_kernel(const int* __restrict__ dst, int* __restrict__ deg) {
  int e = blockIdx.x * blockDim.x + threadIdx.x;
  if (e < N_EDGES) atomicAdd(&deg[dst[e]], 1);
}

// Parallel scan: 196 co-resident blocks, local scan + publish + lookback.
__global__ __launch_bounds__(256) void scan_kernel(
    const int* __restrict__ deg, int* __restrict__ offsets,
    int* __restrict__ cursor, int* blocksum) {
  __shared__ int wsum[4];
  __shared__ int sP;
  const int b = blockIdx.x, t = threadIdx.x, lane = t & 63, wv = t >> 6;
  const int idx = b * 256 + t;
  const int v = (idx < N_NODES) ? deg[idx] : 0;
  int inc = v;
#pragma unroll
  for (int d = 1; d < 64; d <<= 1) {
    int n = __shfl_up(inc, d);
    if (lane >= d) inc += n;
  }
  if (lane == 63) wsum[wv] = inc;
  __syncthreads();
  int woff = 0;
  for (int j = 0; j < wv; ++j) woff += wsum[j];
  const int linc = inc + woff;           // block-inclusive prefix
  if (t == 255) atomicExch(&blocksum[b], linc);   // publish block total
  if (wv == 0) {                         // lane-parallel lookback
    int p = 0;
    for (int j = lane; j < b; j += 64) {
      int s;
      do { s = atomicAdd(&blocksum[j], 0); } while (s == -1);
      p += s;
    }
#pragma unroll
    for (int d = 1; d < 64; d <<= 1) p += __shfl_xor(p, d);
    if (lane == 0) sP = p;
  }
  __syncthreads();
  const int excl = sP + linc - v;
  if (idx < N_NODES) { offsets[idx] = excl; cursor[idx] = excl; }
  if (idx == N_NODES) offsets[N_NODES] = excl;   // grand total (v==0 here)
}

__global__ void scatter_kernel(const int* __restrict__ src, const int* __restrict__ dst,
                               int* __restrict__ cursor, int* __restrict__ ssrc) {
  int e = blockIdx.x * blockDim.x + threadIdx.x;
  if (e >= E_TOT) return;
  int d, s;
  if (e < N_EDGES) { d = dst[e]; s = src[e]; }
  else { d = e - N_EDGES; s = d; }
  int pos = atomicAdd(&cursor[d], 1);
  ssrc[pos] = s;
}

// ---------------- Layer 1 + GEMM2 fused ------------------------------------
// 4 waves/block, one node per wave (online softmax as before) -> h row in LDS
// -> in-block gemm2 (W2 staged in LDS) -> write xl2/xr2 directly. No h array.
__global__ __launch_bounds__(256) void layer1_gemm2_kernel(
    const unsigned short* __restrict__ xlb, const float* __restrict__ xrA,
    const int* __restrict__ offsets, const int* __restrict__ ssrc,
    const float* __restrict__ att1, const float* __restrict__ b1,
    const float* __restrict__ W2l, const float* __restrict__ W2r,
    float* __restrict__ xl2, float* __restrict__ xr2) {
  __shared__ float Wl[HC * D2];      // 16 KB
  __shared__ float Wr[HC * D2];      // 16 KB
  __shared__ float hs[4][HC];        // 4 KB
  const int t = threadIdx.x;
  const int lane = t & 63;
  const int wv = t >> 6;
  // stage W2 early; latency hides under the edge loop below
  for (int idx = t; idx < HC * D2; idx += 256) { Wl[idx] = W2l[idx]; Wr[idx] = W2r[idx]; }

  const int i = blockIdx.x * 4 + wv;             // node (50000 = 12500*4 exact)
  const int lane4 = lane << 2;
  const float4 xr = *(const float4*)(xrA + (size_t)i * HC + lane4);
  const float4 av = *(const float4*)(att1 + lane4);
  const int e0 = offsets[i], e1 = offsets[i + 1];
  float m = -INFINITY, s = 0.f;
  float acc0 = 0.f, acc1 = 0.f, acc2 = 0.f, acc3 = 0.f;
  ushort4 vc = *(const ushort4*)(xlb + (size_t)ssrc[e0] * HC + lane4);
  for (int e = e0; e < e1; ++e) {
    const int jn = (e + 1 < e1) ? ssrc[e + 1] : 0;
    const ushort4 vn = *(const ushort4*)(xlb + (size_t)jn * HC + lane4);
    const float v0 = bf2f(vc.x), v1 = bf2f(vc.y), v2 = bf2f(vc.z), v3 = bf2f(vc.w);
    float p = lrelu(v0 + xr.x) * av.x + lrelu(v1 + xr.y) * av.y +
              lrelu(v2 + xr.z) * av.z + lrelu(v3 + xr.w) * av.w;
    p += __shfl_xor(p, 1);
    p += __shfl_xor(p, 2);
    p += __shfl_xor(p, 4);
    if (p > m) {
      const float f = __expf(m - p);
      s *= f; acc0 *= f; acc1 *= f; acc2 *= f; acc3 *= f;
      m = p;
    }
    const float w = __expf(p - m);
    s += w;
    acc0 += w * v0; acc1 += w * v1; acc2 += w * v2; acc3 += w * v3;
    vc = vn;
  }
  const float inv = 1.f / s;
  float r0 = acc0 * inv + b1[lane4 + 0];
  float r1 = acc1 * inv + b1[lane4 + 1];
  float r2 = acc2 * inv + b1[lane4 + 2];
  float r3 = acc3 * inv + b1[lane4 + 3];
  r0 = r0 > 0.f ? r0 : __expf(r0) - 1.f;
  r1 = r1 > 0.f ? r1 : __expf(r1) - 1.f;
  r2 = r2 > 0.f ? r2 : __expf(r2) - 1.f;
  r3 = r3 > 0.f ? r3 : __expf(r3) - 1.f;
  hs[wv][lane4 + 0] = r0; hs[wv][lane4 + 1] = r1;
  hs[wv][lane4 + 2] = r2; hs[wv][lane4 + 3] = r3;
  __syncthreads();   // hs + W2 staged

  // gemm2: node = wv's 64 lanes; c = lane&15, group g = lane>>4 handles k = g::4
  // (stride-4 k -> W2 LDS reads are 2-way bank aliased = free; hs reads broadcast)
  const int c = lane & 15;
  const int g = lane >> 4;
  float al = 0.f, ar = 0.f;
#pragma unroll 16
  for (int kk = 0; kk < 64; ++kk) {
    const int k = g + (kk << 2);
    const float hv = hs[wv][k];
    al += hv * Wl[k * D2 + c];
    ar += hv * Wr[k * D2 + c];
  }
  al += __shfl_xor(al, 16); al += __shfl_xor(al, 32);
  ar += __shfl_xor(ar, 16); ar += __shfl_xor(ar, 32);
  if (g == 0) {
    xl2[i * D2 + c] = al;
    xr2[i * D2 + c] = ar;
  }
}

// ---------------- Layer 2 + log_softmax: 16 lanes per node ----------------
__global__ __launch_bounds__(256) void layer2_kernel(
    const float* __restrict__ xl2, const float* __restrict__ xr2,
    const int* __restrict__ offsets, const int* __restrict__ ssrc,
    const float* __restrict__ att2, const float* __restrict__ b2,
    float* __restrict__ out) {
  const int gtid = blockIdx.x * blockDim.x + threadIdx.x;
  const int node = gtid >> 4;
  const int c = gtid & 15;
  if (node >= N_NODES) return;
  const float xr = xr2[node * D2 + c];
  const float av = att2[c];
  const int e0 = offsets[node], e1 = offsets[node + 1];
  float m = -INFINITY, s = 0.f, acc = 0.f;
  for (int e = e0; e < e1; ++e) {
    const int j = ssrc[e];
    const float v = xl2[j * D2 + c];
    float p = lrelu(v + xr) * av;
    p += __shfl_xor(p, 1);
    p += __shfl_xor(p, 2);
    p += __shfl_xor(p, 4);
    p += __shfl_xor(p, 8);
    if (p > m) {
      const float f = __expf(m - p);
      s *= f; acc *= f;
      m = p;
    }
    const float w = __expf(p - m);
    s += w;
    acc += w * v;
  }
  const float o = acc / s + b2[c];
  out[(size_t)node * D2 + c] = o;
  float mx = o;
#pragma unroll
  for (int d = 1; d < 16; d <<= 1) mx = fmaxf(mx, __shfl_xor(mx, d));
  float ex = __expf(o - mx);
  float sum = ex;
#pragma unroll
  for (int d = 1; d < 16; d <<= 1) sum += __shfl_xor(sum, d);
  out[(size_t)N_NODES * D2 + (size_t)node * D2 + c] = o - mx - __logf(sum);
}

// ---------------- launch ---------------------------------------------------
extern "C" void kernel_launch(void* const* d_in, const int* in_sizes, int n_in,
                              void* d_out, int out_size, void* d_ws, size_t ws_size,
                              hipStream_t stream) {
  const float* x    = (const float*)d_in[0];
  const int*   ei   = (const int*)d_in[1];
  const float* W1l  = (const float*)d_in[2];
  const float* W1r  = (const float*)d_in[3];
  const float* att1 = (const float*)d_in[4];
  const float* b1   = (const float*)d_in[5];
  const float* W2l  = (const float*)d_in[6];
  const float* W2r  = (const float*)d_in[7];
  const float* att2 = (const float*)d_in[8];
  const float* b2   = (const float*)d_in[9];
  const int* esrc = ei;
  const int* edst = ei + N_EDGES;
  float* out = (float*)d_out;

  char* ws = (char*)d_ws;
  unsigned short* xlb = (unsigned short*)ws;  ws += (size_t)N_NODES * HC * 2;  // 25.6 MB
  float* xrA = (float*)ws;                    ws += (size_t)N_NODES * HC * 4;  // 51.2 MB
  // union region: xb (bf16 x) lives only until gemm1; everything below it
  // is written strictly after gemm1 completes (stream-serial order below).
  char* region = ws;                          ws += (size_t)N_NODES * DIM_IN * 2; // 76.8 MB
  unsigned short* xb = (unsigned short*)region;
  float* xl2 = (float*)(region + (size_t)N_NODES * HC * 4);      //  3.2 MB
  float* xr2 = (float*)(region + (size_t)N_NODES * HC * 4 + (size_t)N_NODES * D2 * 4);
  char* intsBase = region + (size_t)N_NODES * HC * 4 + 2 * (size_t)N_NODES * D2 * 4;
  int* deg      = (int*)intsBase;
  int* offsets  = (int*)(intsBase + 200192);
  int* cursor   = (int*)(intsBase + 400384);
  int* ssrc     = (int*)(intsBase + 600576);                     // 1.8 MB
  int* blocksum = (int*)(intsBase + 600576 + 1800192);           // 784 B
  unsigned short* wt = (unsigned short*)ws;   ws += (size_t)NB * DIM_IN * 2;   // 0.79 MB

  convxw_kernel<<<3584, 256, 0, stream>>>(x, W1l, W1r, xb, wt);
  gemm1_mfma<<<dim3((N_NODES + 127) / 128, NB / 128), 256, 0, stream>>>(xb, wt, xlb, xrA);
  // CSR build AFTER gemm1 (its buffers alias xb)
  init_deg_kernel<<<SCAN_B, 256, 0, stream>>>(deg, blocksum);
  hist_kernel<<<(N_EDGES + 255) / 256, 256, 0, stream>>>(edst, deg);
  scan_kernel<<<SCAN_B, 256, 0, stream>>>(deg, offsets, cursor, blocksum);
  scatter_kernel<<<(E_TOT + 255) / 256, 256, 0, stream>>>(esrc, edst, cursor, ssrc);
  layer1_gemm2_kernel<<<N_NODES / 4, 256, 0, stream>>>(
      xlb, xrA, offsets, ssrc, att1, b1, W2l, W2r, xl2, xr2);
  layer2_kernel<<<(N_NODES * D2 + 255) / 256, 256, 0, stream>>>(xl2, xr2, offsets, ssrc, att2, b2, out);
}

// Round 14
// 482.333 us; speedup vs baseline: 1.8982x; 1.1038x over previous
//
#include <hip/hip_runtime.h>
#include <math.h>

#define N_NODES 50000
#define N_EDGES 400000
#define E_TOT   450000     // edges + self loops
#define DIM_IN  768
#define HC      256        // heads * dim_h = 8*32
#define D2      16
#define NB      512        // gemm1 output cols (xl | xr)
#define NKT     12         // K-tiles: 768 / 64
#define SCAN_B  196        // scan blocks (<= CU count -> co-resident, lookback safe)

typedef __attribute__((ext_vector_type(8))) short short8v;   // 8 bf16 (4 VGPR)
typedef __attribute__((ext_vector_type(4))) float f32x4;     // MFMA acc

__device__ __forceinline__ float lrelu(float x) { return x > 0.f ? x : 0.2f * x; }

// fp32 -> bf16 round-to-nearest-even
__device__ __forceinline__ unsigned short f2bf(float f) {
  unsigned int u = __float_as_uint(f);
  unsigned int r = u + 0x7fffu + ((u >> 16) & 1u);
  return (unsigned short)(r >> 16);
}
__device__ __forceinline__ float bf2f(unsigned short u) {
  return __uint_as_float(((unsigned int)u) << 16);
}

// ---------------- fused: convert x to bf16 + build WcatT bf16 --------------
// blocks [0,1536): wt[512][768] = [W1l|W1r]^T ; blocks [1536,3584): x -> xb
__global__ __launch_bounds__(256) void convxw_kernel(
    const float* __restrict__ x, const float* __restrict__ W1l,
    const float* __restrict__ W1r, unsigned short* __restrict__ xb,
    unsigned short* __restrict__ wt) {
  const int bid = blockIdx.x;
  const int t = threadIdx.x;
  if (bid < 1536) {                       // 1536*256 == 512*768 exactly
    const int idx = bid * 256 + t;
    const int n = idx / DIM_IN, k = idx - n * DIM_IN;
    const float v = (n < HC) ? W1l[(size_t)k * HC + n] : W1r[(size_t)k * HC + (n - HC)];
    wt[idx] = f2bf(v);
  } else {
    const int ntask = (N_NODES * DIM_IN) / 8;
    const int stride = 2048 * 256;
    for (int i = (bid - 1536) * 256 + t; i < ntask; i += stride) {
      const float4 a = ((const float4*)x)[2 * (size_t)i];
      const float4 b = ((const float4*)x)[2 * (size_t)i + 1];
      short8v v;
      v[0] = (short)f2bf(a.x); v[1] = (short)f2bf(a.y);
      v[2] = (short)f2bf(a.z); v[3] = (short)f2bf(a.w);
      v[4] = (short)f2bf(b.x); v[5] = (short)f2bf(b.y);
      v[6] = (short)f2bf(b.z); v[7] = (short)f2bf(b.w);
      ((short8v*)xb)[i] = v;
    }
  }
}

// ---------------- GEMM1 (bf16 MFMA): [xl|xr] = x @ [W1l|W1r] ---------------
// UNCHANGED from round 11 (88.5 us, MfmaUtil 17%).
__global__ __launch_bounds__(256) void gemm1_mfma(
    const unsigned short* __restrict__ xb, const unsigned short* __restrict__ wt,
    unsigned short* __restrict__ xlb, float* __restrict__ xrA) {
  __shared__ unsigned short Al[2][128 * 64];   // 2 x 16 KB
  __shared__ unsigned short Bl[2][128 * 64];   // 2 x 16 KB
  const int t = threadIdx.x;
  const int lane = t & 63;
  const int w = t >> 6;            // wave 0..3
  const int wr = w >> 1, wc = w & 1;
  const int bm0 = blockIdx.x * 128;
  const int bn0 = blockIdx.y * 128;

  const int r8 = lane >> 3;                         // row within group 0..7
  const int swz_cb = ((lane & 7) << 4) ^ (r8 << 4); // pre-swizzled source col byte

  f32x4 acc[4][4];
#pragma unroll
  for (int m = 0; m < 4; ++m)
#pragma unroll
    for (int n = 0; n < 4; ++n) acc[m][n] = (f32x4)0.f;

  const int fr = lane & 15;     // frag row/col
  const int kg = lane >> 4;     // k-group 0..3
  const int swr = (fr & 7) << 4;

  auto stage = [&](int buf, int k0) {
#pragma unroll
    for (int q = 0; q < 4; ++q) {
      const int rg = w * 4 + q;
      int grow = bm0 + rg * 8 + r8;
      grow = grow < N_NODES ? grow : N_NODES - 1;   // clamp (dup rows, stores guarded)
      const char* src = (const char*)(xb + (size_t)grow * DIM_IN + k0) + swz_cb;
      __builtin_amdgcn_global_load_lds(
          (const __attribute__((address_space(1))) void*)src,
          (__attribute__((address_space(3))) void*)((char*)Al + buf * 16384 + rg * 1024),
          16, 0, 0);
    }
#pragma unroll
    for (int q = 0; q < 4; ++q) {
      const int rg = w * 4 + q;
      const int brow = bn0 + rg * 8 + r8;
      const char* src = (const char*)(wt + (size_t)brow * DIM_IN + k0) + swz_cb;
      __builtin_amdgcn_global_load_lds(
          (const __attribute__((address_space(1))) void*)src,
          (__attribute__((address_space(3))) void*)((char*)Bl + buf * 16384 + rg * 1024),
          16, 0, 0);
    }
  };

  stage(0, 0);
  __syncthreads();   // tile 0 visible

  int cur = 0;
  for (int kt = 0; kt < NKT; ++kt) {
    if (kt + 1 < NKT) stage(cur ^ 1, (kt + 1) * 64);   // issue next tile FIRST

    const char* Ab = (const char*)Al + cur * 16384;
    const char* Bb = (const char*)Bl + cur * 16384;
    short8v af[4][2], bf[4][2];
#pragma unroll
    for (int m = 0; m < 4; ++m) {
      const int row = wr * 64 + m * 16 + fr;
#pragma unroll
      for (int ks = 0; ks < 2; ++ks) {
        const int cb = (ks * 64 + kg * 16) ^ swr;
        af[m][ks] = *(const short8v*)(Ab + row * 128 + cb);
      }
    }
#pragma unroll
    for (int n = 0; n < 4; ++n) {
      const int row = wc * 64 + n * 16 + fr;
#pragma unroll
      for (int ks = 0; ks < 2; ++ks) {
        const int cb = (ks * 64 + kg * 16) ^ swr;
        bf[n][ks] = *(const short8v*)(Bb + row * 128 + cb);
      }
    }
#pragma unroll
    for (int ks = 0; ks < 2; ++ks)
#pragma unroll
      for (int m = 0; m < 4; ++m)
#pragma unroll
        for (int n = 0; n < 4; ++n)
          acc[m][n] = __builtin_amdgcn_mfma_f32_16x16x32_bf16(
              af[m][ks], bf[n][ks], acc[m][n], 0, 0, 0);

    if (kt + 1 < NKT) {
      __syncthreads();
      cur ^= 1;
    }
  }

  const bool isXl = (bn0 < HC);
#pragma unroll
  for (int m = 0; m < 4; ++m) {
    const int grow_base = bm0 + wr * 64 + m * 16 + kg * 4;
#pragma unroll
    for (int n = 0; n < 4; ++n) {
      const int gcol = bn0 + wc * 64 + n * 16 + fr;
#pragma unroll
      for (int r = 0; r < 4; ++r) {
        const int grow = grow_base + r;
        if (grow < N_NODES) {
          if (isXl) xlb[(size_t)grow * HC + gcol] = f2bf(acc[m][n][r]);
          else      xrA[(size_t)grow * HC + (gcol - HC)] = acc[m][n][r];
        }
      }
    }
  }
}

// ---------------- CSR build ------------------------------------------------
__global__ void init_deg_kernel(int* __restrict__ deg, int* __restrict__ blocksum) {
  int i = blockIdx.x * blockDim.x + threadIdx.x;
  if (i < N_NODES) deg[i] = 1;   // self loop
  if (i < SCAN_B) blocksum[i] = -1;   // lookback sentinel
}

__global__ void hist_kernel(const int* __restrict__ dst, int* __restrict__ deg) {
  int e = blockIdx.x * blockDim.x + threadIdx.x;
  if (e < N_EDGES) atomicAdd(&deg[dst[e]], 1);
}

// Parallel scan: 196 co-resident blocks, local scan + publish + lookback.
__global__ __launch_bounds__(256) void scan_kernel(
    const int* __restrict__ deg, int* __restrict__ offsets,
    int* __restrict__ cursor, int* blocksum) {
  __shared__ int wsum[4];
  __shared__ int sP;
  const int b = blockIdx.x, t = threadIdx.x, lane = t & 63, wv = t >> 6;
  const int idx = b * 256 + t;
  const int v = (idx < N_NODES) ? deg[idx] : 0;
  int inc = v;
#pragma unroll
  for (int d = 1; d < 64; d <<= 1) {
    int n = __shfl_up(inc, d);
    if (lane >= d) inc += n;
  }
  if (lane == 63) wsum[wv] = inc;
  __syncthreads();
  int woff = 0;
  for (int j = 0; j < wv; ++j) woff += wsum[j];
  const int linc = inc + woff;           // block-inclusive prefix
  if (t == 255) atomicExch(&blocksum[b], linc);   // publish block total
  if (wv == 0) {                         // lane-parallel lookback
    int p = 0;
    for (int j = lane; j < b; j += 64) {
      int s;
      do { s = atomicAdd(&blocksum[j], 0); } while (s == -1);
      p += s;
    }
#pragma unroll
    for (int d = 1; d < 64; d <<= 1) p += __shfl_xor(p, d);
    if (lane == 0) sP = p;
  }
  __syncthreads();
  const int excl = sP + linc - v;
  if (idx < N_NODES) { offsets[idx] = excl; cursor[idx] = excl; }
  if (idx == N_NODES) offsets[N_NODES] = excl;   // grand total (v==0 here)
}

__global__ void scatter_kernel(const int* __restrict__ src, const int* __restrict__ dst,
                               int* __restrict__ cursor, int* __restrict__ ssrc) {
  int e = blockIdx.x * blockDim.x + threadIdx.x;
  if (e >= E_TOT) return;
  int d, s;
  if (e < N_EDGES) { d = dst[e]; s = src[e]; }
  else { d = e - N_EDGES; s = d; }
  int pos = atomicAdd(&cursor[d], 1);
  ssrc[pos] = s;
}

// ---------------- Layer 1 + GEMM2 fused (v2) --------------------------------
// Fixes vs round 13: (1) LDS 36->20 KB via packed-bf16 W2 (8 blocks/CU);
// (2) 2-way edge-interleaved online softmax (2 independent states, merged) --
// halves the serial dependent chain, doubles outstanding gathers;
// (3) branchless max-update (no divergent rescale branch).
__global__ __launch_bounds__(256) void layer1_gemm2_kernel(
    const unsigned short* __restrict__ xlb, const float* __restrict__ xrA,
    const int* __restrict__ offsets, const int* __restrict__ ssrc,
    const float* __restrict__ att1, const float* __restrict__ b1,
    const float* __restrict__ W2l, const float* __restrict__ W2r,
    float* __restrict__ xl2, float* __restrict__ xr2) {
  __shared__ unsigned int Wp[HC * D2];   // 16 KB: lo16=Wl bf16, hi16=Wr bf16
  __shared__ float hs[4][HC];            // 4 KB
  const int t = threadIdx.x;
  const int lane = t & 63;
  const int wv = t >> 6;
  // stage packed W2 early; latency hides under the edge loop below
  for (int idx = t; idx < HC * D2; idx += 256) {
    const unsigned int lo = f2bf(W2l[idx]);
    const unsigned int hi = f2bf(W2r[idx]);
    Wp[idx] = lo | (hi << 16);
  }

  const int i = blockIdx.x * 4 + wv;             // node (50000 = 12500*4 exact)
  const int lane4 = lane << 2;
  const float4 xr = *(const float4*)(xrA + (size_t)i * HC + lane4);
  const float4 av = *(const float4*)(att1 + lane4);
  const int e0 = offsets[i], e1 = offsets[i + 1];

  // two independent online-softmax states (even/odd edges)
  float ma = -INFINITY, sa = 0.f, a0 = 0.f, a1 = 0.f, a2 = 0.f, a3 = 0.f;
  float mb = -INFINITY, sb = 0.f, b0v = 0.f, b1v = 0.f, b2v = 0.f, b3v = 0.f;

  int e = e0;
  for (; e + 1 < e1; e += 2) {
    const int ja = ssrc[e], jb = ssrc[e + 1];
    const ushort4 va = *(const ushort4*)(xlb + (size_t)ja * HC + lane4);
    const ushort4 vb = *(const ushort4*)(xlb + (size_t)jb * HC + lane4);
    const float va0 = bf2f(va.x), va1 = bf2f(va.y), va2 = bf2f(va.z), va3 = bf2f(va.w);
    const float vb0 = bf2f(vb.x), vb1 = bf2f(vb.y), vb2 = bf2f(vb.z), vb3 = bf2f(vb.w);
    float pa = lrelu(va0 + xr.x) * av.x + lrelu(va1 + xr.y) * av.y +
               lrelu(va2 + xr.z) * av.z + lrelu(va3 + xr.w) * av.w;
    float pb = lrelu(vb0 + xr.x) * av.x + lrelu(vb1 + xr.y) * av.y +
               lrelu(vb2 + xr.z) * av.z + lrelu(vb3 + xr.w) * av.w;
    pa += __shfl_xor(pa, 1); pb += __shfl_xor(pb, 1);
    pa += __shfl_xor(pa, 2); pb += __shfl_xor(pb, 2);
    pa += __shfl_xor(pa, 4); pb += __shfl_xor(pb, 4);
    // branchless updates
    {
      const float mn = fmaxf(ma, pa);
      const float f = __expf(ma - mn);    // first iter: ma=-inf -> 0
      const float w = __expf(pa - mn);
      sa = sa * f + w;
      a0 = a0 * f + w * va0; a1 = a1 * f + w * va1;
      a2 = a2 * f + w * va2; a3 = a3 * f + w * va3;
      ma = mn;
    }
    {
      const float mn = fmaxf(mb, pb);
      const float f = __expf(mb - mn);
      const float w = __expf(pb - mn);
      sb = sb * f + w;
      b0v = b0v * f + w * vb0; b1v = b1v * f + w * vb1;
      b2v = b2v * f + w * vb2; b3v = b3v * f + w * vb3;
      mb = mn;
    }
  }
  if (e < e1) {   // tail edge -> state A (A always gets >=1 edge)
    const int ja = ssrc[e];
    const ushort4 va = *(const ushort4*)(xlb + (size_t)ja * HC + lane4);
    const float va0 = bf2f(va.x), va1 = bf2f(va.y), va2 = bf2f(va.z), va3 = bf2f(va.w);
    float pa = lrelu(va0 + xr.x) * av.x + lrelu(va1 + xr.y) * av.y +
               lrelu(va2 + xr.z) * av.z + lrelu(va3 + xr.w) * av.w;
    pa += __shfl_xor(pa, 1);
    pa += __shfl_xor(pa, 2);
    pa += __shfl_xor(pa, 4);
    const float mn = fmaxf(ma, pa);
    const float f = __expf(ma - mn);
    const float w = __expf(pa - mn);
    sa = sa * f + w;
    a0 = a0 * f + w * va0; a1 = a1 * f + w * va1;
    a2 = a2 * f + w * va2; a3 = a3 * f + w * va3;
    ma = mn;
  }
  // merge B into A (mb may be -inf when node degree == 1 -> fb = 0)
  const float M = fmaxf(ma, mb);
  const float fa = __expf(ma - M);
  const float fb = __expf(mb - M);
  const float s = sa * fa + sb * fb;
  const float inv = 1.f / s;
  float r0 = (a0 * fa + b0v * fb) * inv + b1[lane4 + 0];
  float r1 = (a1 * fa + b1v * fb) * inv + b1[lane4 + 1];
  float r2 = (a2 * fa + b2v * fb) * inv + b1[lane4 + 2];
  float r3 = (a3 * fa + b3v * fb) * inv + b1[lane4 + 3];
  r0 = r0 > 0.f ? r0 : __expf(r0) - 1.f;
  r1 = r1 > 0.f ? r1 : __expf(r1) - 1.f;
  r2 = r2 > 0.f ? r2 : __expf(r2) - 1.f;
  r3 = r3 > 0.f ? r3 : __expf(r3) - 1.f;
  hs[wv][lane4 + 0] = r0; hs[wv][lane4 + 1] = r1;
  hs[wv][lane4 + 2] = r2; hs[wv][lane4 + 3] = r3;
  __syncthreads();   // hs + Wp staged

  // gemm2: c = lane&15, group g = lane>>4 handles k = g::4
  // (Wp reads: groups 0/2 share banks 0-15, 1/3 share 16-31 -> 2-way = free;
  //  hs reads broadcast within 16-lane group)
  const int c = lane & 15;
  const int g = lane >> 4;
  float al = 0.f, ar = 0.f;
#pragma unroll 16
  for (int kk = 0; kk < 64; ++kk) {
    const int k = g + (kk << 2);
    const float hv = hs[wv][k];
    const unsigned int wp = Wp[k * D2 + c];
    al += hv * bf2f((unsigned short)(wp & 0xffffu));
    ar += hv * bf2f((unsigned short)(wp >> 16));
  }
  al += __shfl_xor(al, 16); al += __shfl_xor(al, 32);
  ar += __shfl_xor(ar, 16); ar += __shfl_xor(ar, 32);
  if (g == 0) {
    xl2[i * D2 + c] = al;
    xr2[i * D2 + c] = ar;
  }
}

// ---------------- Layer 2 + log_softmax: 16 lanes per node ----------------
__global__ __launch_bounds__(256) void layer2_kernel(
    const float* __restrict__ xl2, const float* __restrict__ xr2,
    const int* __restrict__ offsets, const int* __restrict__ ssrc,
    const float* __restrict__ att2, const float* __restrict__ b2,
    float* __restrict__ out) {
  const int gtid = blockIdx.x * blockDim.x + threadIdx.x;
  const int node = gtid >> 4;
  const int c = gtid & 15;
  if (node >= N_NODES) return;
  const float xr = xr2[node * D2 + c];
  const float av = att2[c];
  const int e0 = offsets[node], e1 = offsets[node + 1];
  float m = -INFINITY, s = 0.f, acc = 0.f;
  for (int e = e0; e < e1; ++e) {
    const int j = ssrc[e];
    const float v = xl2[j * D2 + c];
    float p = lrelu(v + xr) * av;
    p += __shfl_xor(p, 1);
    p += __shfl_xor(p, 2);
    p += __shfl_xor(p, 4);
    p += __shfl_xor(p, 8);
    if (p > m) {
      const float f = __expf(m - p);
      s *= f; acc *= f;
      m = p;
    }
    const float w = __expf(p - m);
    s += w;
    acc += w * v;
  }
  const float o = acc / s + b2[c];
  out[(size_t)node * D2 + c] = o;
  float mx = o;
#pragma unroll
  for (int d = 1; d < 16; d <<= 1) mx = fmaxf(mx, __shfl_xor(mx, d));
  float ex = __expf(o - mx);
  float sum = ex;
#pragma unroll
  for (int d = 1; d < 16; d <<= 1) sum += __shfl_xor(sum, d);
  out[(size_t)N_NODES * D2 + (size_t)node * D2 + c] = o - mx - __logf(sum);
}

// ---------------- launch ---------------------------------------------------
extern "C" void kernel_launch(void* const* d_in, const int* in_sizes, int n_in,
                              void* d_out, int out_size, void* d_ws, size_t ws_size,
                              hipStream_t stream) {
  const float* x    = (const float*)d_in[0];
  const int*   ei   = (const int*)d_in[1];
  const float* W1l  = (const float*)d_in[2];
  const float* W1r  = (const float*)d_in[3];
  const float* att1 = (const float*)d_in[4];
  const float* b1   = (const float*)d_in[5];
  const float* W2l  = (const float*)d_in[6];
  const float* W2r  = (const float*)d_in[7];
  const float* att2 = (const float*)d_in[8];
  const float* b2   = (const float*)d_in[9];
  const int* esrc = ei;
  const int* edst = ei + N_EDGES;
  float* out = (float*)d_out;

  char* ws = (char*)d_ws;
  unsigned short* xlb = (unsigned short*)ws;  ws += (size_t)N_NODES * HC * 2;  // 25.6 MB
  float* xrA = (float*)ws;                    ws += (size_t)N_NODES * HC * 4;  // 51.2 MB
  // union region: xb (bf16 x) lives only until gemm1; everything below it
  // is written strictly after gemm1 completes (stream-serial order below).
  char* region = ws;                          ws += (size_t)N_NODES * DIM_IN * 2; // 76.8 MB
  unsigned short* xb = (unsigned short*)region;
  float* xl2 = (float*)(region + (size_t)N_NODES * HC * 4);      //  3.2 MB
  float* xr2 = (float*)(region + (size_t)N_NODES * HC * 4 + (size_t)N_NODES * D2 * 4);
  char* intsBase = region + (size_t)N_NODES * HC * 4 + 2 * (size_t)N_NODES * D2 * 4;
  int* deg      = (int*)intsBase;
  int* offsets  = (int*)(intsBase + 200192);
  int* cursor   = (int*)(intsBase + 400384);
  int* ssrc     = (int*)(intsBase + 600576);                     // 1.8 MB
  int* blocksum = (int*)(intsBase + 600576 + 1800192);           // 784 B
  unsigned short* wt = (unsigned short*)ws;   ws += (size_t)NB * DIM_IN * 2;   // 0.79 MB

  convxw_kernel<<<3584, 256, 0, stream>>>(x, W1l, W1r, xb, wt);
  gemm1_mfma<<<dim3((N_NODES + 127) / 128, NB / 128), 256, 0, stream>>>(xb, wt, xlb, xrA);
  // CSR build AFTER gemm1 (its buffers alias xb)
  init_deg_kernel<<<SCAN_B, 256, 0, stream>>>(deg, blocksum);
  hist_kernel<<<(N_EDGES + 255) / 256, 256, 0, stream>>>(edst, deg);
  scan_kernel<<<SCAN_B, 256, 0, stream>>>(deg, offsets, cursor, blocksum);
  scatter_kernel<<<(E_TOT + 255) / 256, 256, 0, stream>>>(esrc, edst, cursor, ssrc);
  layer1_gemm2_kernel<<<N_NODES / 4, 256, 0, stream>>>(
      xlb, xrA, offsets, ssrc, att1, b1, W2l, W2r, xl2, xr2);
  layer2_kernel<<<(N_NODES * D2 + 255) / 256, 256, 0, stream>>>(xl2, xr2, offsets, ssrc, att2, b2, out);
}